// Round 6
// baseline (2731.050 us; speedup 1.0000x reference)
//
#include <hip/hip_runtime.h>
#include <hip/hip_bf16.h>

// ---------------------------------------------------------------------------
// VisionMamba, round 17: R12 pipeline (1421us verified) + 4 measurement
// probes. Probes are copies of the four layer kernels run x48/x24 with a
// register-carried serialization dep (sign bit of computed data -> input
// address offset), launched AFTER the loop on dead buffers. They exceed the
// 42us harness fills -> land in rocprof top-5 -> per-kernel times = dur/N.
// d_out is never touched by probes; wall time this round is sacrificial.
//
// Evidence: R13 3780 (device barriers), R14 2042 (XCD pinning), R15 1916
// (front fusion, 64us fused kernel), R16 1731 (LDS-staged tables REGRESSED
// conv by +13us/layer -> streaming x_proj was already fine; barriers cost).
// Conclusion: stop inferring, measure the gi/cv/sc/gl split directly.
// ---------------------------------------------------------------------------

#define NTOK   1568   // B * L
#define DMODEL 192
#define DINNER 384
#define DSTATE 16
#define DTRANK 12
#define DEPTH  24
#define LSEQ   196
#define TCH    49     // scan time-chunk (196 = 4*49)
#define LDA    40     // LDS row stride in bf16 elements (80B)

typedef __attribute__((ext_vector_type(8))) short short8;
typedef __attribute__((ext_vector_type(4))) short short4v;
typedef __attribute__((ext_vector_type(4))) float floatx4;

__device__ inline short f2bf(float f) {
    __hip_bfloat16 h = __float2bfloat16(f);
    return *reinterpret_cast<short*>(&h);
}

// ---------------- merged pre-stage: weight cvt + transposes + im2col ----------------
#define PR1 884736
#define PR2 1327104   // +442368
#define PR3 1363968   // +36864
#define PR4 1769472   // +405504
#define PR5 1880064   // +110592
#define PR6 3084288   // +1204224
__global__ __launch_bounds__(256) void prep(
    const float* __restrict__ inw, const float* __restrict__ outw,
    const float* __restrict__ pew, const float* __restrict__ xpw,
    const float* __restrict__ dtw, const float* __restrict__ x,
    short* __restrict__ w_in, short* __restrict__ w_out,
    short* __restrict__ w_pe, float* __restrict__ xpwT,
    float* __restrict__ dtwT, __hip_bfloat16* __restrict__ patches)
{
    int idx = blockIdx.x * 256 + threadIdx.x;
    if (idx < PR3) {
        float4 v; short* dst;
        if (idx < PR1)      { v = ((const float4*)inw)[idx];        dst = w_in  + (size_t)idx * 4; }
        else if (idx < PR2) { int i = idx - PR1; v = ((const float4*)outw)[i]; dst = w_out + (size_t)i * 4; }
        else                { int i = idx - PR2; v = ((const float4*)pew)[i];  dst = w_pe  + (size_t)i * 4; }
        short4v o;
        o[0] = f2bf(v.x); o[1] = f2bf(v.y); o[2] = f2bf(v.z); o[3] = f2bf(v.w);
        *(short4v*)dst = o;
    } else if (idx < PR4) {
        int i = idx - PR3;                    // xpwT[layer][k][e] = xpw[layer][e][k]
        int layer = i / 16896, rem = i % 16896;
        int k = rem / 44, e = rem % 44;
        xpwT[i] = xpw[(size_t)layer * 16896 + e * 384 + k];
    } else if (idx < PR5) {
        int i = idx - PR4;                    // dtwT[layer][r][d] = dtw[layer][d][r]
        int layer = i / 4608, rem = i % 4608;
        int r = rem / 384, d = rem % 384;
        dtwT[i] = dtw[(size_t)layer * 4608 + d * 12 + r];
    } else if (idx < PR6) {
        int i = idx - PR5;                    // im2col
        int tok = i / 768, e = i % 768;
        int b = tok / LSEQ, l = tok % LSEQ;
        int py = l / 14, px = l % 14;
        int ic = e >> 8, rem = e & 255, ky = rem >> 4, kx = rem & 15;
        patches[i] = __float2bfloat16(x[((b * 3 + ic) * 224 + py * 16 + ky) * 224 + px * 16 + kx]);
    }
}

// ---------------- gemm_in: xz[M,768] = hn[M,192] @ W[768,192]^T ----------------
template<int K>
__global__ __launch_bounds__(256) void gemm_in(
    const __hip_bfloat16* __restrict__ A, const short* __restrict__ Wb,
    float* __restrict__ C, int M, int N)
{
    __shared__ short As[64 * LDA];
    __shared__ short Ws[64 * LDA];
    int tid = threadIdx.x;
    int m0 = blockIdx.x * 64, n0 = blockIdx.y * 64;
    int wv = tid >> 6, lane = tid & 63;
    int fm = lane & 15, q = lane >> 4;
    int row = tid >> 2, kc = (tid & 3) * 8;
    const short* Ab = (const short*)A;
    floatx4 acc[4];
#pragma unroll
    for (int nt = 0; nt < 4; ++nt) acc[nt] = (floatx4){0.f, 0.f, 0.f, 0.f};

#pragma unroll
    for (int k0 = 0; k0 < K; k0 += 32) {
        {
            int m = m0 + row;
            short8 v = {0,0,0,0,0,0,0,0};
            if (m < M) v = *(const short8*)&Ab[(size_t)m * K + k0 + kc];
            *(short8*)&As[row * LDA + kc] = v;
        }
        {
            short8 w = *(const short8*)&Wb[(size_t)(n0 + row) * K + k0 + kc];
            *(short8*)&Ws[row * LDA + kc] = w;
        }
        __syncthreads();
        short8 af = *(const short8*)&As[(wv * 16 + fm) * LDA + q * 8];
#pragma unroll
        for (int nt = 0; nt < 4; ++nt) {
            short8 bf = *(const short8*)&Ws[(nt * 16 + fm) * LDA + q * 8];
            acc[nt] = __builtin_amdgcn_mfma_f32_16x16x32_bf16(af, bf, acc[nt], 0, 0, 0);
        }
        __syncthreads();
    }
#pragma unroll
    for (int nt = 0; nt < 4; ++nt) {
        int col = n0 + nt * 16 + fm;
#pragma unroll
        for (int r = 0; r < 4; ++r) {
            int mrow = m0 + wv * 16 + q * 4 + r;
            if (mrow < M) C[(size_t)mrow * N + col] = acc[nt][r];
        }
    }
}

// ---------------- gemm_ln: 16-row tiles, pipelined LDS, fused residual+LN ----------------
template<int K>
__global__ __launch_bounds__(256) void gemm_ln(
    const __hip_bfloat16* __restrict__ A, const short* __restrict__ Wb,
    const float* __restrict__ bias, float* __restrict__ residual,
    __hip_bfloat16* __restrict__ hn, float* __restrict__ outf,
    const float* __restrict__ lnw, const float* __restrict__ lnb,
    int accumulate)
{
    __shared__ short As[16 * LDA];
    __shared__ short Ws[192 * LDA];
    __shared__ float slw[192], slb[192], sbias[192];
    __shared__ float sS1[4][16], sS2[4][16];
    int tid = threadIdx.x;
    int m0 = blockIdx.x * 16;
    int wv = tid >> 6, lane = tid & 63;
    int fm = lane & 15, q = lane >> 4;
    int wrow = tid >> 2, kc = (tid & 3) * 8;
    if (tid < 192) {
        slw[tid] = lnw[tid];
        slb[tid] = lnb[tid];
        sbias[tid] = bias ? bias[tid] : 0.f;
    }
    const short* Ab = (const short*)A;
    floatx4 acc[3];
#pragma unroll
    for (int j = 0; j < 3; ++j) acc[j] = (floatx4){0.f, 0.f, 0.f, 0.f};

    short8 aR = {0,0,0,0,0,0,0,0};
    short8 wR[3];
    if (tid < 64) aR = *(const short8*)&Ab[(size_t)(m0 + (tid >> 2)) * K + kc];
#pragma unroll
    for (int j = 0; j < 3; ++j)
        wR[j] = *(const short8*)&Wb[(size_t)(wrow + 64 * j) * K + kc];

    for (int k0 = 0; k0 < K; k0 += 32) {
        if (tid < 64) *(short8*)&As[(tid >> 2) * LDA + kc] = aR;
#pragma unroll
        for (int j = 0; j < 3; ++j)
            *(short8*)&Ws[(wrow + 64 * j) * LDA + kc] = wR[j];
        __syncthreads();
        int kn = k0 + 32;
        if (kn < K) {
            if (tid < 64) aR = *(const short8*)&Ab[(size_t)(m0 + (tid >> 2)) * K + kn + kc];
#pragma unroll
            for (int j = 0; j < 3; ++j)
                wR[j] = *(const short8*)&Wb[(size_t)(wrow + 64 * j) * K + kn + kc];
        }
        short8 af = *(const short8*)&As[fm * LDA + q * 8];
#pragma unroll
        for (int j = 0; j < 3; ++j) {
            int ct = wv * 3 + j;
            short8 bf = *(const short8*)&Ws[(ct * 16 + fm) * LDA + q * 8];
            acc[j] = __builtin_amdgcn_mfma_f32_16x16x32_bf16(af, bf, acc[j], 0, 0, 0);
        }
        __syncthreads();
    }

    float v[3][4];
#pragma unroll
    for (int r = 0; r < 4; ++r) {
        int m = m0 + q * 4 + r;
#pragma unroll
        for (int j = 0; j < 3; ++j) {
            int col = (wv * 3 + j) * 16 + fm;
            float t = acc[j][r] + sbias[col];
            if (accumulate) t += residual[(size_t)m * DMODEL + col];
            v[j][r] = t;
        }
    }
#pragma unroll
    for (int r = 0; r < 4; ++r) {
        int m = m0 + q * 4 + r;
#pragma unroll
        for (int j = 0; j < 3; ++j)
            residual[(size_t)m * DMODEL + (wv * 3 + j) * 16 + fm] = v[j][r];
    }
#pragma unroll
    for (int r = 0; r < 4; ++r) {
        float s1 = v[0][r] + v[1][r] + v[2][r];
        float s2 = v[0][r]*v[0][r] + v[1][r]*v[1][r] + v[2][r]*v[2][r];
        s1 += __shfl_xor(s1, 1); s2 += __shfl_xor(s2, 1);
        s1 += __shfl_xor(s1, 2); s2 += __shfl_xor(s2, 2);
        s1 += __shfl_xor(s1, 4); s2 += __shfl_xor(s2, 4);
        s1 += __shfl_xor(s1, 8); s2 += __shfl_xor(s2, 8);
        if (fm == 0) { sS1[wv][q * 4 + r] = s1; sS2[wv][q * 4 + r] = s2; }
    }
    __syncthreads();
#pragma unroll
    for (int r = 0; r < 4; ++r) {
        int row = q * 4 + r;
        int m = m0 + row;
        float S1 = sS1[0][row] + sS1[1][row] + sS1[2][row] + sS1[3][row];
        float S2 = sS2[0][row] + sS2[1][row] + sS2[2][row] + sS2[3][row];
        float mean = S1 * (1.f / DMODEL);
        float var  = S2 * (1.f / DMODEL) - mean * mean;
        float rstd = rsqrtf(var + 1e-5f);
#pragma unroll
        for (int j = 0; j < 3; ++j) {
            int col = (wv * 3 + j) * 16 + fm;
            float o = (v[j][r] - mean) * rstd * slw[col] + slb[col];
            if (outf) outf[(size_t)m * DMODEL + col] = o;
            else      hn[(size_t)m * DMODEL + col] = __float2bfloat16(o);
        }
    }
}

// ---------------- conv + silu + x_proj + dt : 4 tokens/block (R12 original) ----------
__global__ __launch_bounds__(256) void conv_xproj_dt(
    const float* __restrict__ xz, const float* __restrict__ cw,
    const float* __restrict__ cb, const float* __restrict__ xpwT,
    const float* __restrict__ dtwT, const float* __restrict__ dtb,
    float* __restrict__ u, float* __restrict__ dtg, float* __restrict__ bcg)
{
    __shared__ float sxz[7 * 384];
    __shared__ float su[4 * 384];
    __shared__ float sx[4 * 48];
    int blk = blockIdx.x;
    int b = blk / 49, c = blk % 49;
    int l0 = c * 4;
    int tid = threadIdx.x;

    for (int idx = tid; idx < 7 * 384; idx += 256) {
        int t = idx / 384, d = idx % 384;
        int l = l0 - 3 + t;
        sxz[idx] = (l >= 0) ? xz[(size_t)(b * LSEQ + l) * 768 + d] : 0.f;
    }
    __syncthreads();

    for (int idx = tid; idx < 4 * 384; idx += 256) {
        int t = idx / 384, d = idx % 384;
        float4 w4 = *(const float4*)&cw[d * 4];
        float acc = cb[d]
            + sxz[t * 384 + d]       * w4.x
            + sxz[(t + 1) * 384 + d] * w4.y
            + sxz[(t + 2) * 384 + d] * w4.z
            + sxz[(t + 3) * 384 + d] * w4.w;
        float sig = 1.f / (1.f + __expf(-acc));
        float val = acc * sig;
        su[idx] = val;
        u[(size_t)(b * LSEQ + l0 + t) * 384 + d] = val;
    }
    __syncthreads();

    {
        int wv = tid >> 6, e = tid & 63;
        if (e < 44) {
            float a0 = 0.f, a1 = 0.f, a2 = 0.f, a3 = 0.f;
            const float* ur = &su[wv * 384];
            for (int j = 0; j < 384; j += 4) {
                a0 += ur[j]     * xpwT[(j    ) * 44 + e];
                a1 += ur[j + 1] * xpwT[(j + 1) * 44 + e];
                a2 += ur[j + 2] * xpwT[(j + 2) * 44 + e];
                a3 += ur[j + 3] * xpwT[(j + 3) * 44 + e];
            }
            sx[wv * 48 + e] = (a0 + a1) + (a2 + a3);
        }
    }
    __syncthreads();

    for (int idx = tid; idx < 4 * 384; idx += 256) {
        int t = idx / 384, d = idx % 384;
        float acc = dtb[d];
#pragma unroll
        for (int r = 0; r < DTRANK; ++r) acc += sx[t * 48 + r] * dtwT[r * 384 + d];
        float sp = (acc > 20.f) ? acc : log1pf(__expf(acc));
        dtg[(size_t)(b * LSEQ + l0 + t) * 384 + d] = sp;
    }
    if (tid < 128) {
        int t = tid >> 5, j = tid & 31;
        bcg[(size_t)(b * LSEQ + l0 + t) * 32 + j] = sx[t * 48 + 12 + j];
    }
}

// ---------------- selective scan + gating (3-phase, R7) ----------------
#define SPAD 272
__global__ __launch_bounds__(256) void scan_kernel(
    const float* __restrict__ u, const float* __restrict__ dtg,
    const float* __restrict__ bc, const float* __restrict__ xz,
    const float* __restrict__ Alog, const float* __restrict__ Dp,
    __hip_bfloat16* __restrict__ y)
{
    __shared__ float sdt[TCH][16];
    __shared__ float su_[TCH][16];
    __shared__ float sz_[TCH][16];
    __shared__ float sB_[TCH][16];
    __shared__ float sC_[TCH][16];
    __shared__ float sprod[TCH][SPAD];

    int b  = blockIdx.x / 24;
    int dg = blockIdx.x % 24;
    int tid = threadIdx.x;
    int s = tid & 15, dl = tid >> 4;
    int d = dg * 16 + dl;
    float Ads = -expf(Alog[d * DSTATE + s]);
    float Dd2 = Dp[dg * 16 + (tid & 15)];
    float h = 0.f;

    for (int c0 = 0; c0 < LSEQ; c0 += TCH) {
        if (tid < TCH * 4) {
            int t = tid >> 2, j4 = (tid & 3) * 4;
            size_t tok = (size_t)(b * LSEQ + c0 + t);
            *(float4*)&sdt[t][j4] = *(const float4*)&dtg[tok * DINNER + dg * 16 + j4];
            *(float4*)&su_[t][j4] = *(const float4*)&u  [tok * DINNER + dg * 16 + j4];
            *(float4*)&sz_[t][j4] = *(const float4*)&xz [tok * 768 + DINNER + dg * 16 + j4];
            *(float4*)&sB_[t][j4] = *(const float4*)&bc [tok * 32 + j4];
            *(float4*)&sC_[t][j4] = *(const float4*)&bc [tok * 32 + 16 + j4];
        }
        __syncthreads();

#pragma unroll 7
        for (int t = 0; t < TCH; ++t) {
            float dtv = sdt[t][dl];
            float uv  = su_[t][dl];
            float Bv  = sB_[t][s];
            float Cv  = sC_[t][s];
            float dA  = __expf(dtv * Ads);
            h = dA * h + (dtv * uv) * Bv;
            sprod[t][dl * 17 + s] = h * Cv;
        }
        __syncthreads();

        for (int i = tid; i < TCH * 16; i += 256) {
            int t = i >> 4, dl2 = i & 15;
            float sum = 0.f;
#pragma unroll
            for (int j = 0; j < 16; ++j) sum += sprod[t][dl2 * 17 + j];
            float uv = su_[t][dl2];
            float zv = sz_[t][dl2];
            float sig = 1.f / (1.f + __expf(-zv));
            y[(size_t)(b * LSEQ + c0 + t) * DINNER + dg * 16 + dl2] =
                __float2bfloat16((sum + uv * Dd2) * (zv * sig));
        }
        __syncthreads();
    }
}

// =========================== MEASUREMENT PROBES ===========================
// Copies of the four layer kernels, iterated with a register-carried dep:
// poff = sign bit of data computed in iter i, added (x8 bf16 / x4 f32 to keep
// 16B alignment) to iter i+1's input addresses. Outputs go to dead buffers.

__global__ __launch_bounds__(256) void gi_probe(
    const __hip_bfloat16* __restrict__ A, const short* __restrict__ Wb,
    float* __restrict__ C, int M, int N)
{
    __shared__ short As[64 * LDA];
    __shared__ short Ws[64 * LDA];
    int tid = threadIdx.x;
    int m0 = blockIdx.x * 64, n0 = blockIdx.y * 64;
    int wv = tid >> 6, lane = tid & 63;
    int fm = lane & 15, q = lane >> 4;
    int row = tid >> 2, kc = (tid & 3) * 8;
    const short* Ab = (const short*)A;
    int poff = 0;
    for (int iter = 0; iter < 48; ++iter) {
        floatx4 acc[4];
#pragma unroll
        for (int nt = 0; nt < 4; ++nt) acc[nt] = (floatx4){0.f, 0.f, 0.f, 0.f};
#pragma unroll
        for (int k0 = 0; k0 < 192; k0 += 32) {
            {
                int m = m0 + row;
                short8 v = {0,0,0,0,0,0,0,0};
                if (m < M) v = *(const short8*)&Ab[(size_t)m * 192 + k0 + kc + poff * 8];
                *(short8*)&As[row * LDA + kc] = v;
            }
            {
                short8 w = *(const short8*)&Wb[(size_t)(n0 + row) * 192 + k0 + kc];
                *(short8*)&Ws[row * LDA + kc] = w;
            }
            __syncthreads();
            short8 af = *(const short8*)&As[(wv * 16 + fm) * LDA + q * 8];
#pragma unroll
            for (int nt = 0; nt < 4; ++nt) {
                short8 bf = *(const short8*)&Ws[(nt * 16 + fm) * LDA + q * 8];
                acc[nt] = __builtin_amdgcn_mfma_f32_16x16x32_bf16(af, bf, acc[nt], 0, 0, 0);
            }
            __syncthreads();
        }
#pragma unroll
        for (int nt = 0; nt < 4; ++nt) {
            int col = n0 + nt * 16 + fm;
#pragma unroll
            for (int r = 0; r < 4; ++r) {
                int mrow = m0 + wv * 16 + q * 4 + r;
                if (mrow < M) C[(size_t)mrow * N + col] = acc[nt][r];
            }
        }
        poff = (int)(__float_as_uint(acc[0][0]) >> 31);
    }
}

__global__ __launch_bounds__(256) void cv_probe(
    const float* __restrict__ xz, const float* __restrict__ cw,
    const float* __restrict__ cb, const float* __restrict__ xpwT,
    const float* __restrict__ dtwT, const float* __restrict__ dtb,
    float* __restrict__ u, float* __restrict__ dtg, float* __restrict__ bcg)
{
    __shared__ float sxz[7 * 384];
    __shared__ float su[4 * 384];
    __shared__ float sx[4 * 48];
    int blk = blockIdx.x;
    int b = blk / 49, c = blk % 49;
    int l0 = c * 4;
    int tid = threadIdx.x;
    int poff = 0;
    for (int iter = 0; iter < 24; ++iter) {
        float dep = 0.f;
        for (int idx = tid; idx < 7 * 384; idx += 256) {
            int t = idx / 384, d = idx % 384;
            int l = l0 - 3 + t;
            sxz[idx] = (l >= 0) ? xz[(size_t)(b * LSEQ + l) * 768 + d + poff * 4] : 0.f;
        }
        __syncthreads();
        for (int idx = tid; idx < 4 * 384; idx += 256) {
            int t = idx / 384, d = idx % 384;
            float4 w4 = *(const float4*)&cw[d * 4];
            float acc = cb[d]
                + sxz[t * 384 + d]       * w4.x
                + sxz[(t + 1) * 384 + d] * w4.y
                + sxz[(t + 2) * 384 + d] * w4.z
                + sxz[(t + 3) * 384 + d] * w4.w;
            float sig = 1.f / (1.f + __expf(-acc));
            float val = acc * sig;
            su[idx] = val;
            u[(size_t)(b * LSEQ + l0 + t) * 384 + d] = val;
        }
        __syncthreads();
        {
            int wv = tid >> 6, e = tid & 63;
            if (e < 44) {
                float a0 = 0.f, a1 = 0.f, a2 = 0.f, a3 = 0.f;
                const float* ur = &su[wv * 384];
                for (int j = 0; j < 384; j += 4) {
                    a0 += ur[j]     * xpwT[(j    ) * 44 + e];
                    a1 += ur[j + 1] * xpwT[(j + 1) * 44 + e];
                    a2 += ur[j + 2] * xpwT[(j + 2) * 44 + e];
                    a3 += ur[j + 3] * xpwT[(j + 3) * 44 + e];
                }
                sx[wv * 48 + e] = (a0 + a1) + (a2 + a3);
            }
        }
        __syncthreads();
        for (int idx = tid; idx < 4 * 384; idx += 256) {
            int t = idx / 384, d = idx % 384;
            float acc = dtb[d];
#pragma unroll
            for (int r = 0; r < DTRANK; ++r) acc += sx[t * 48 + r] * dtwT[r * 384 + d];
            float sp = (acc > 20.f) ? acc : log1pf(__expf(acc));
            dtg[(size_t)(b * LSEQ + l0 + t) * 384 + d] = sp;
            dep += sp;
        }
        if (tid < 128) {
            int t = tid >> 5, j = tid & 31;
            bcg[(size_t)(b * LSEQ + l0 + t) * 32 + j] = sx[t * 48 + 12 + j];
        }
        __syncthreads();
        poff = (int)(__float_as_uint(dep - 1.f) >> 31) & 1;
    }
}

__global__ __launch_bounds__(256) void sc_probe(
    const float* __restrict__ u, const float* __restrict__ dtg,
    const float* __restrict__ bc, const float* __restrict__ xz,
    const float* __restrict__ Alog, const float* __restrict__ Dp,
    __hip_bfloat16* __restrict__ y)
{
    __shared__ float sdt[TCH][16];
    __shared__ float su_[TCH][16];
    __shared__ float sz_[TCH][16];
    __shared__ float sB_[TCH][16];
    __shared__ float sC_[TCH][16];
    __shared__ float sprod[TCH][SPAD];

    int b  = blockIdx.x / 24;
    int dg = blockIdx.x % 24;
    int tid = threadIdx.x;
    int s = tid & 15, dl = tid >> 4;
    int d = dg * 16 + dl;
    float Ads = -expf(Alog[d * DSTATE + s]);
    float Dd2 = Dp[dg * 16 + (tid & 15)];
    int poff = 0;
    for (int iter = 0; iter < 48; ++iter) {
        float h = 0.f, dep = 0.f;
        for (int c0 = 0; c0 < LSEQ; c0 += TCH) {
            if (tid < TCH * 4) {
                int t = tid >> 2, j4 = (tid & 3) * 4;
                size_t tok = (size_t)(b * LSEQ + c0 + t);
                *(float4*)&sdt[t][j4] = *(const float4*)&dtg[tok * DINNER + dg * 16 + j4 + poff * 4];
                *(float4*)&su_[t][j4] = *(const float4*)&u  [tok * DINNER + dg * 16 + j4 + poff * 4];
                *(float4*)&sz_[t][j4] = *(const float4*)&xz [tok * 768 + DINNER + dg * 16 + j4 + poff * 4];
                *(float4*)&sB_[t][j4] = *(const float4*)&bc [tok * 32 + j4];
                *(float4*)&sC_[t][j4] = *(const float4*)&bc [tok * 32 + 16 + j4];
            }
            __syncthreads();
#pragma unroll 7
            for (int t = 0; t < TCH; ++t) {
                float dtv = sdt[t][dl];
                float uv  = su_[t][dl];
                float Bv  = sB_[t][s];
                float Cv  = sC_[t][s];
                float dA  = __expf(dtv * Ads);
                h = dA * h + (dtv * uv) * Bv;
                sprod[t][dl * 17 + s] = h * Cv;
            }
            __syncthreads();
            for (int i = tid; i < TCH * 16; i += 256) {
                int t = i >> 4, dl2 = i & 15;
                float sum = 0.f;
#pragma unroll
                for (int j = 0; j < 16; ++j) sum += sprod[t][dl2 * 17 + j];
                float uv = su_[t][dl2];
                float zv = sz_[t][dl2];
                float sig = 1.f / (1.f + __expf(-zv));
                float ov = (sum + uv * Dd2) * (zv * sig);
                y[(size_t)(b * LSEQ + c0 + t) * DINNER + dg * 16 + dl2] = __float2bfloat16(ov);
                dep += ov;
            }
            __syncthreads();
        }
        poff = (int)(__float_as_uint(dep) >> 31);
    }
}

__global__ __launch_bounds__(256) void gl_probe(
    const __hip_bfloat16* __restrict__ A, const short* __restrict__ Wb,
    float* __restrict__ residual, __hip_bfloat16* __restrict__ hn,
    const float* __restrict__ lnw, const float* __restrict__ lnb)
{
    __shared__ short As[16 * LDA];
    __shared__ short Ws[192 * LDA];
    __shared__ float slw[192], slb[192];
    __shared__ float sS1[4][16], sS2[4][16];
    int tid = threadIdx.x;
    int m0 = blockIdx.x * 16;
    int wv = tid >> 6, lane = tid & 63;
    int fm = lane & 15, q = lane >> 4;
    int wrow = tid >> 2, kc = (tid & 3) * 8;
    if (tid < 192) { slw[tid] = lnw[tid]; slb[tid] = lnb[tid]; }
    const short* Ab = (const short*)A;
    int poff = 0;
    for (int iter = 0; iter < 48; ++iter) {
        floatx4 acc[3];
#pragma unroll
        for (int j = 0; j < 3; ++j) acc[j] = (floatx4){0.f, 0.f, 0.f, 0.f};
        for (int k0 = 0; k0 < 384; k0 += 32) {
            if (tid < 64)
                *(short8*)&As[(tid >> 2) * LDA + kc] =
                    *(const short8*)&Ab[(size_t)(m0 + (tid >> 2)) * 384 + k0 + kc + poff * 8];
#pragma unroll
            for (int j = 0; j < 3; ++j)
                *(short8*)&Ws[(wrow + 64 * j) * LDA + kc] =
                    *(const short8*)&Wb[(size_t)(wrow + 64 * j) * 384 + k0 + kc];
            __syncthreads();
            short8 af = *(const short8*)&As[fm * LDA + q * 8];
#pragma unroll
            for (int j = 0; j < 3; ++j) {
                int ct = wv * 3 + j;
                short8 bf = *(const short8*)&Ws[(ct * 16 + fm) * LDA + q * 8];
                acc[j] = __builtin_amdgcn_mfma_f32_16x16x32_bf16(af, bf, acc[j], 0, 0, 0);
            }
            __syncthreads();
        }
        float v[3][4];
#pragma unroll
        for (int r = 0; r < 4; ++r) {
            int m = m0 + q * 4 + r;
#pragma unroll
            for (int j = 0; j < 3; ++j) {
                int col = (wv * 3 + j) * 16 + fm;
                v[j][r] = acc[j][r] + residual[(size_t)m * DMODEL + col + poff * 4 - poff * 4]
                        + (float)poff * 0.f;
            }
        }
#pragma unroll
        for (int r = 0; r < 4; ++r) {
            int m = m0 + q * 4 + r;
#pragma unroll
            for (int j = 0; j < 3; ++j)
                residual[(size_t)m * DMODEL + (wv * 3 + j) * 16 + fm] = v[j][r] * 0.25f;
        }
#pragma unroll
        for (int r = 0; r < 4; ++r) {
            float s1 = v[0][r] + v[1][r] + v[2][r];
            float s2 = v[0][r]*v[0][r] + v[1][r]*v[1][r] + v[2][r]*v[2][r];
            s1 += __shfl_xor(s1, 1); s2 += __shfl_xor(s2, 1);
            s1 += __shfl_xor(s1, 2); s2 += __shfl_xor(s2, 2);
            s1 += __shfl_xor(s1, 4); s2 += __shfl_xor(s2, 4);
            s1 += __shfl_xor(s1, 8); s2 += __shfl_xor(s2, 8);
            if (fm == 0) { sS1[wv][q * 4 + r] = s1; sS2[wv][q * 4 + r] = s2; }
        }
        __syncthreads();
        float depv = 0.f;
#pragma unroll
        for (int r = 0; r < 4; ++r) {
            int row = q * 4 + r;
            int m = m0 + row;
            float S1 = sS1[0][row] + sS1[1][row] + sS1[2][row] + sS1[3][row];
            float S2 = sS2[0][row] + sS2[1][row] + sS2[2][row] + sS2[3][row];
            float mean = S1 * (1.f / DMODEL);
            float var  = S2 * (1.f / DMODEL) - mean * mean;
            float rstd = rsqrtf(var + 1e-5f);
#pragma unroll
            for (int j = 0; j < 3; ++j) {
                int col = (wv * 3 + j) * 16 + fm;
                float o = (v[j][r] - mean) * rstd * slw[col] + slb[col];
                hn[(size_t)m * DMODEL + col] = __float2bfloat16(o);
                depv += o;
            }
        }
        __syncthreads();
        poff = (int)(__float_as_uint(depv) >> 31);
    }
}

// ---------------------------------------------------------------------------
extern "C" void kernel_launch(void* const* d_in, const int* in_sizes, int n_in,
                              void* d_out, int out_size, void* d_ws, size_t ws_size,
                              hipStream_t stream)
{
    const float* x         = (const float*)d_in[0];
    const float* pe_w      = (const float*)d_in[1];
    const float* pe_b      = (const float*)d_in[2];
    const float* norm_w    = (const float*)d_in[3];
    const float* norm_b    = (const float*)d_in[4];
    const float* in_proj_w = (const float*)d_in[5];
    const float* conv_w    = (const float*)d_in[6];
    const float* conv_b    = (const float*)d_in[7];
    const float* xproj_w   = (const float*)d_in[8];
    const float* dtproj_w  = (const float*)d_in[9];
    const float* dtproj_b  = (const float*)d_in[10];
    const float* A_log     = (const float*)d_in[11];
    const float* D_param   = (const float*)d_in[12];
    const float* outproj_w = (const float*)d_in[13];
    const float* normf_w   = (const float*)d_in[14];
    const float* normf_b   = (const float*)d_in[15];

    float* ws = (float*)d_ws;
    float* residual = ws;                       // 301056 f32
    float* xz       = residual + 301056;        // 1204224 f32
    float* ubuf     = xz + 1204224;             // 602112 f32
    float* dtbuf    = ubuf + 602112;            // 602112 f32
    float* bcbuf    = dtbuf + 602112;           // 50176 f32
    __hip_bfloat16* hn      = (__hip_bfloat16*)(ws + 2759680);  // 301056 bf16
    __hip_bfloat16* ybf     = (__hip_bfloat16*)(ws + 2910208);  // 602112 bf16
    __hip_bfloat16* patches = (__hip_bfloat16*)(ws + 3211264);  // 1204224 bf16
    short* w_in  = (short*)(ws + 3813376);      // 3538944 bf16
    short* w_out = (short*)(ws + 5582848);      // 1769472 bf16
    short* w_pe  = (short*)(ws + 6467584);      // 147456 bf16
    float* xpwT  = ws + 6541312;                // 405504 f32
    float* dtwT  = xpwT + 405504;               // 110592 f32

    prep<<<12048, 256, 0, stream>>>(
        in_proj_w, outproj_w, pe_w, xproj_w, dtproj_w, x,
        w_in, w_out, w_pe, xpwT, dtwT, patches);
    gemm_ln<768><<<98, 256, 0, stream>>>(
        patches, w_pe, pe_b, residual, hn, nullptr, norm_w, norm_b, 0);

    for (int i = 0; i < DEPTH; ++i) {
        int last = (i == DEPTH - 1);
        gemm_in<192><<<dim3(25, 12), 256, 0, stream>>>(
            hn, w_in + (size_t)i * 768 * DMODEL, xz, NTOK, 768);
        conv_xproj_dt<<<392, 256, 0, stream>>>(
            xz, conv_w + (size_t)i * DINNER * 4, conv_b + (size_t)i * DINNER,
            xpwT + (size_t)i * 384 * 44, dtwT + (size_t)i * 12 * 384,
            dtproj_b + (size_t)i * DINNER, ubuf, dtbuf, bcbuf);
        scan_kernel<<<192, 256, 0, stream>>>(
            ubuf, dtbuf, bcbuf, xz, A_log + (size_t)i * DINNER * DSTATE,
            D_param + (size_t)i * DINNER, ybf);
        gemm_ln<384><<<98, 256, 0, stream>>>(
            ybf, w_out + (size_t)i * DMODEL * DINNER, nullptr, residual, hn,
            last ? (float*)d_out : nullptr,
            last ? normf_w : norm_w + (i + 1) * DMODEL,
            last ? normf_b : norm_b + (i + 1) * DMODEL,
            1);
    }

    // ---- measurement probes (all buffers below are dead; d_out untouched) ----
    gi_probe<<<dim3(25, 12), 256, 0, stream>>>(hn, w_in, xz, NTOK, 768);
    cv_probe<<<392, 256, 0, stream>>>(
        xz, conv_w, conv_b, xpwT, dtwT, dtproj_b, ubuf, dtbuf, bcbuf);
    sc_probe<<<192, 256, 0, stream>>>(
        ubuf, dtbuf, bcbuf, xz, A_log, D_param, ybf);
    gl_probe<<<98, 256, 0, stream>>>(
        ybf, w_out, residual, hn, norm_w, norm_b);
}

// Round 7
// 1615.353 us; speedup vs baseline: 1.6907x; 1.6907x over previous
//
#include <hip/hip_runtime.h>
#include <hip/hip_bf16.h>

// ---------------------------------------------------------------------------
// VisionMamba, round 18: R12 pipeline (1421us verified) + rewritten scan.
// B=8, L=196, D_MODEL=192, D_INNER=384, D_STATE=16, DT_RANK=12, DEPTH=24.
//
// R17 probe data: scan=13.8us (biggest kernel), gi~5, cv~8, gl~4.5 ->
// ~31us kernels + ~26us launch gaps per 57us layer. Scan was LDS-throughput
// bound: 4 b32 reads + 1 write per thread per t (~23K cyc DS) + sprod
// phase-3 (~4.5K cyc). Fix (this round's single change):
//  - transposed LDS [ch][t] pad-52 -> one float4 read covers 4 t-steps
//    (wave reads are row-broadcast; 2-way bank aliasing only = free)
//  - DPP row reduction (quad_perm/row_ror, pure VALU) replaces the
//    sprod write + 16-read phase 3; sy[49][16] keeps y-writes coalesced.
// Predicted scan ~4-5us -> wall ~1210.
// ---------------------------------------------------------------------------

#define NTOK   1568   // B * L
#define DMODEL 192
#define DINNER 384
#define DSTATE 16
#define DTRANK 12
#define DEPTH  24
#define LSEQ   196
#define TCH    49     // scan time-chunk (196 = 4*49)
#define TPAD   52     // padded t-stride (52 f32 = 208 B; 16B-aligned, 2-way banks)
#define LDA    40     // LDS row stride in bf16 elements (80B)

typedef __attribute__((ext_vector_type(8))) short short8;
typedef __attribute__((ext_vector_type(4))) short short4v;
typedef __attribute__((ext_vector_type(4))) float floatx4;

__device__ inline short f2bf(float f) {
    __hip_bfloat16 h = __float2bfloat16(f);
    return *reinterpret_cast<short*>(&h);
}

// 16-lane (DPP row) sum: every lane of each 16-lane row ends with the row sum.
// xor1/xor2 via quad_perm, then row_ror:4 + row_ror:8. Pure VALU, no DS pipe.
__device__ __forceinline__ float rowsum16(float x) {
    float v = x;
    int i;
    i = __builtin_amdgcn_mov_dpp(__float_as_int(v), 0xB1, 0xf, 0xf, false);  // quad_perm [1,0,3,2]
    v += __int_as_float(i);
    i = __builtin_amdgcn_mov_dpp(__float_as_int(v), 0x4E, 0xf, 0xf, false);  // quad_perm [2,3,0,1]
    v += __int_as_float(i);
    i = __builtin_amdgcn_mov_dpp(__float_as_int(v), 0x124, 0xf, 0xf, false); // row_ror:4
    v += __int_as_float(i);
    i = __builtin_amdgcn_mov_dpp(__float_as_int(v), 0x128, 0xf, 0xf, false); // row_ror:8
    v += __int_as_float(i);
    return v;
}

// ---------------- merged pre-stage: weight cvt + transposes + im2col ----------------
#define PR1 884736
#define PR2 1327104   // +442368
#define PR3 1363968   // +36864
#define PR4 1769472   // +405504
#define PR5 1880064   // +110592
#define PR6 3084288   // +1204224
__global__ __launch_bounds__(256) void prep(
    const float* __restrict__ inw, const float* __restrict__ outw,
    const float* __restrict__ pew, const float* __restrict__ xpw,
    const float* __restrict__ dtw, const float* __restrict__ x,
    short* __restrict__ w_in, short* __restrict__ w_out,
    short* __restrict__ w_pe, float* __restrict__ xpwT,
    float* __restrict__ dtwT, __hip_bfloat16* __restrict__ patches)
{
    int idx = blockIdx.x * 256 + threadIdx.x;
    if (idx < PR3) {
        float4 v; short* dst;
        if (idx < PR1)      { v = ((const float4*)inw)[idx];        dst = w_in  + (size_t)idx * 4; }
        else if (idx < PR2) { int i = idx - PR1; v = ((const float4*)outw)[i]; dst = w_out + (size_t)i * 4; }
        else                { int i = idx - PR2; v = ((const float4*)pew)[i];  dst = w_pe  + (size_t)i * 4; }
        short4v o;
        o[0] = f2bf(v.x); o[1] = f2bf(v.y); o[2] = f2bf(v.z); o[3] = f2bf(v.w);
        *(short4v*)dst = o;
    } else if (idx < PR4) {
        int i = idx - PR3;                    // xpwT[layer][k][e] = xpw[layer][e][k]
        int layer = i / 16896, rem = i % 16896;
        int k = rem / 44, e = rem % 44;
        xpwT[i] = xpw[(size_t)layer * 16896 + e * 384 + k];
    } else if (idx < PR5) {
        int i = idx - PR4;                    // dtwT[layer][r][d] = dtw[layer][d][r]
        int layer = i / 4608, rem = i % 4608;
        int r = rem / 384, d = rem % 384;
        dtwT[i] = dtw[(size_t)layer * 4608 + d * 12 + r];
    } else if (idx < PR6) {
        int i = idx - PR5;                    // im2col
        int tok = i / 768, e = i % 768;
        int b = tok / LSEQ, l = tok % LSEQ;
        int py = l / 14, px = l % 14;
        int ic = e >> 8, rem = e & 255, ky = rem >> 4, kx = rem & 15;
        patches[i] = __float2bfloat16(x[((b * 3 + ic) * 224 + py * 16 + ky) * 224 + px * 16 + kx]);
    }
}

// ---------------- gemm_in: xz[M,768] = hn[M,192] @ W[768,192]^T ----------------
template<int K>
__global__ __launch_bounds__(256) void gemm_in(
    const __hip_bfloat16* __restrict__ A, const short* __restrict__ Wb,
    float* __restrict__ C, int M, int N)
{
    __shared__ short As[64 * LDA];
    __shared__ short Ws[64 * LDA];
    int tid = threadIdx.x;
    int m0 = blockIdx.x * 64, n0 = blockIdx.y * 64;
    int wv = tid >> 6, lane = tid & 63;
    int fm = lane & 15, q = lane >> 4;
    int row = tid >> 2, kc = (tid & 3) * 8;
    const short* Ab = (const short*)A;
    floatx4 acc[4];
#pragma unroll
    for (int nt = 0; nt < 4; ++nt) acc[nt] = (floatx4){0.f, 0.f, 0.f, 0.f};

#pragma unroll
    for (int k0 = 0; k0 < K; k0 += 32) {
        {
            int m = m0 + row;
            short8 v = {0,0,0,0,0,0,0,0};
            if (m < M) v = *(const short8*)&Ab[(size_t)m * K + k0 + kc];
            *(short8*)&As[row * LDA + kc] = v;
        }
        {
            short8 w = *(const short8*)&Wb[(size_t)(n0 + row) * K + k0 + kc];
            *(short8*)&Ws[row * LDA + kc] = w;
        }
        __syncthreads();
        short8 af = *(const short8*)&As[(wv * 16 + fm) * LDA + q * 8];
#pragma unroll
        for (int nt = 0; nt < 4; ++nt) {
            short8 bf = *(const short8*)&Ws[(nt * 16 + fm) * LDA + q * 8];
            acc[nt] = __builtin_amdgcn_mfma_f32_16x16x32_bf16(af, bf, acc[nt], 0, 0, 0);
        }
        __syncthreads();
    }
#pragma unroll
    for (int nt = 0; nt < 4; ++nt) {
        int col = n0 + nt * 16 + fm;
#pragma unroll
        for (int r = 0; r < 4; ++r) {
            int mrow = m0 + wv * 16 + q * 4 + r;
            if (mrow < M) C[(size_t)mrow * N + col] = acc[nt][r];
        }
    }
}

// ---------------- gemm_ln: 16-row tiles, pipelined LDS, fused residual+LN ----------------
template<int K>
__global__ __launch_bounds__(256) void gemm_ln(
    const __hip_bfloat16* __restrict__ A, const short* __restrict__ Wb,
    const float* __restrict__ bias, float* __restrict__ residual,
    __hip_bfloat16* __restrict__ hn, float* __restrict__ outf,
    const float* __restrict__ lnw, const float* __restrict__ lnb,
    int accumulate)
{
    __shared__ short As[16 * LDA];
    __shared__ short Ws[192 * LDA];
    __shared__ float slw[192], slb[192], sbias[192];
    __shared__ float sS1[4][16], sS2[4][16];
    int tid = threadIdx.x;
    int m0 = blockIdx.x * 16;
    int wv = tid >> 6, lane = tid & 63;
    int fm = lane & 15, q = lane >> 4;
    int wrow = tid >> 2, kc = (tid & 3) * 8;
    if (tid < 192) {
        slw[tid] = lnw[tid];
        slb[tid] = lnb[tid];
        sbias[tid] = bias ? bias[tid] : 0.f;
    }
    const short* Ab = (const short*)A;
    floatx4 acc[3];
#pragma unroll
    for (int j = 0; j < 3; ++j) acc[j] = (floatx4){0.f, 0.f, 0.f, 0.f};

    short8 aR = {0,0,0,0,0,0,0,0};
    short8 wR[3];
    if (tid < 64) aR = *(const short8*)&Ab[(size_t)(m0 + (tid >> 2)) * K + kc];
#pragma unroll
    for (int j = 0; j < 3; ++j)
        wR[j] = *(const short8*)&Wb[(size_t)(wrow + 64 * j) * K + kc];

    for (int k0 = 0; k0 < K; k0 += 32) {
        if (tid < 64) *(short8*)&As[(tid >> 2) * LDA + kc] = aR;
#pragma unroll
        for (int j = 0; j < 3; ++j)
            *(short8*)&Ws[(wrow + 64 * j) * LDA + kc] = wR[j];
        __syncthreads();
        int kn = k0 + 32;
        if (kn < K) {
            if (tid < 64) aR = *(const short8*)&Ab[(size_t)(m0 + (tid >> 2)) * K + kn + kc];
#pragma unroll
            for (int j = 0; j < 3; ++j)
                wR[j] = *(const short8*)&Wb[(size_t)(wrow + 64 * j) * K + kn + kc];
        }
        short8 af = *(const short8*)&As[fm * LDA + q * 8];
#pragma unroll
        for (int j = 0; j < 3; ++j) {
            int ct = wv * 3 + j;
            short8 bf = *(const short8*)&Ws[(ct * 16 + fm) * LDA + q * 8];
            acc[j] = __builtin_amdgcn_mfma_f32_16x16x32_bf16(af, bf, acc[j], 0, 0, 0);
        }
        __syncthreads();
    }

    float v[3][4];
#pragma unroll
    for (int r = 0; r < 4; ++r) {
        int m = m0 + q * 4 + r;
#pragma unroll
        for (int j = 0; j < 3; ++j) {
            int col = (wv * 3 + j) * 16 + fm;
            float t = acc[j][r] + sbias[col];
            if (accumulate) t += residual[(size_t)m * DMODEL + col];
            v[j][r] = t;
        }
    }
#pragma unroll
    for (int r = 0; r < 4; ++r) {
        int m = m0 + q * 4 + r;
#pragma unroll
        for (int j = 0; j < 3; ++j)
            residual[(size_t)m * DMODEL + (wv * 3 + j) * 16 + fm] = v[j][r];
    }
#pragma unroll
    for (int r = 0; r < 4; ++r) {
        float s1 = v[0][r] + v[1][r] + v[2][r];
        float s2 = v[0][r]*v[0][r] + v[1][r]*v[1][r] + v[2][r]*v[2][r];
        s1 += __shfl_xor(s1, 1); s2 += __shfl_xor(s2, 1);
        s1 += __shfl_xor(s1, 2); s2 += __shfl_xor(s2, 2);
        s1 += __shfl_xor(s1, 4); s2 += __shfl_xor(s2, 4);
        s1 += __shfl_xor(s1, 8); s2 += __shfl_xor(s2, 8);
        if (fm == 0) { sS1[wv][q * 4 + r] = s1; sS2[wv][q * 4 + r] = s2; }
    }
    __syncthreads();
#pragma unroll
    for (int r = 0; r < 4; ++r) {
        int row = q * 4 + r;
        int m = m0 + row;
        float S1 = sS1[0][row] + sS1[1][row] + sS1[2][row] + sS1[3][row];
        float S2 = sS2[0][row] + sS2[1][row] + sS2[2][row] + sS2[3][row];
        float mean = S1 * (1.f / DMODEL);
        float var  = S2 * (1.f / DMODEL) - mean * mean;
        float rstd = rsqrtf(var + 1e-5f);
#pragma unroll
        for (int j = 0; j < 3; ++j) {
            int col = (wv * 3 + j) * 16 + fm;
            float o = (v[j][r] - mean) * rstd * slw[col] + slb[col];
            if (outf) outf[(size_t)m * DMODEL + col] = o;
            else      hn[(size_t)m * DMODEL + col] = __float2bfloat16(o);
        }
    }
}

// ---------------- conv + silu + x_proj + dt : 4 tokens/block (R12 original) ----------
__global__ __launch_bounds__(256) void conv_xproj_dt(
    const float* __restrict__ xz, const float* __restrict__ cw,
    const float* __restrict__ cb, const float* __restrict__ xpwT,
    const float* __restrict__ dtwT, const float* __restrict__ dtb,
    float* __restrict__ u, float* __restrict__ dtg, float* __restrict__ bcg)
{
    __shared__ float sxz[7 * 384];
    __shared__ float su[4 * 384];
    __shared__ float sx[4 * 48];
    int blk = blockIdx.x;
    int b = blk / 49, c = blk % 49;
    int l0 = c * 4;
    int tid = threadIdx.x;

    for (int idx = tid; idx < 7 * 384; idx += 256) {
        int t = idx / 384, d = idx % 384;
        int l = l0 - 3 + t;
        sxz[idx] = (l >= 0) ? xz[(size_t)(b * LSEQ + l) * 768 + d] : 0.f;
    }
    __syncthreads();

    for (int idx = tid; idx < 4 * 384; idx += 256) {
        int t = idx / 384, d = idx % 384;
        float4 w4 = *(const float4*)&cw[d * 4];
        float acc = cb[d]
            + sxz[t * 384 + d]       * w4.x
            + sxz[(t + 1) * 384 + d] * w4.y
            + sxz[(t + 2) * 384 + d] * w4.z
            + sxz[(t + 3) * 384 + d] * w4.w;
        float sig = 1.f / (1.f + __expf(-acc));
        float val = acc * sig;
        su[idx] = val;
        u[(size_t)(b * LSEQ + l0 + t) * 384 + d] = val;
    }
    __syncthreads();

    {
        int wv = tid >> 6, e = tid & 63;
        if (e < 44) {
            float a0 = 0.f, a1 = 0.f, a2 = 0.f, a3 = 0.f;
            const float* ur = &su[wv * 384];
            for (int j = 0; j < 384; j += 4) {
                a0 += ur[j]     * xpwT[(j    ) * 44 + e];
                a1 += ur[j + 1] * xpwT[(j + 1) * 44 + e];
                a2 += ur[j + 2] * xpwT[(j + 2) * 44 + e];
                a3 += ur[j + 3] * xpwT[(j + 3) * 44 + e];
            }
            sx[wv * 48 + e] = (a0 + a1) + (a2 + a3);
        }
    }
    __syncthreads();

    for (int idx = tid; idx < 4 * 384; idx += 256) {
        int t = idx / 384, d = idx % 384;
        float acc = dtb[d];
#pragma unroll
        for (int r = 0; r < DTRANK; ++r) acc += sx[t * 48 + r] * dtwT[r * 384 + d];
        float sp = (acc > 20.f) ? acc : log1pf(__expf(acc));
        dtg[(size_t)(b * LSEQ + l0 + t) * 384 + d] = sp;
    }
    if (tid < 128) {
        int t = tid >> 5, j = tid & 31;
        bcg[(size_t)(b * LSEQ + l0 + t) * 32 + j] = sx[t * 48 + 12 + j];
    }
}

// ---------------- selective scan: transposed LDS + DPP row reduction ----------------
// Thread (dch = tid>>4, s = tid&15). Serial loop reads 4 t-steps per float4
// (row-broadcast addresses); h-recurrence per (dch,s); C-contraction via
// rowsum16 (VALU DPP) -> sy[t][dch] from s==0 lanes; coalesced epilogue.
__global__ __launch_bounds__(256) void scan_kernel(
    const float* __restrict__ u, const float* __restrict__ dtg,
    const float* __restrict__ bc, const float* __restrict__ xz,
    const float* __restrict__ Alog, const float* __restrict__ Dp,
    __hip_bfloat16* __restrict__ y)
{
    __shared__ float sdtT[16][TPAD];
    __shared__ float suT [16][TPAD];
    __shared__ float szT [16][TPAD];
    __shared__ float sBT [16][TPAD];
    __shared__ float sCT [16][TPAD];
    __shared__ float sy  [TCH][16];

    int b  = blockIdx.x / 24;
    int dg = blockIdx.x % 24;
    int tid = threadIdx.x;
    int s = tid & 15, dch = tid >> 4;
    float Ads = -expf(Alog[(dg * 16 + dch) * DSTATE + s]);
    float Dd  = Dp[dg * 16 + (tid & 15)];   // epilogue channel = tid&15
    float h = 0.f;

#define SCAN_STEP(dtv, uv, Bv, Cv, tt)                      \
    {                                                       \
        float dA = __expf((dtv) * Ads);                     \
        h = dA * h + ((dtv) * (uv)) * (Bv);                 \
        float p = rowsum16(h * (Cv));                       \
        if (s == 0) sy[tt][dch] = p;                        \
    }

    for (int c0 = 0; c0 < LSEQ; c0 += TCH) {
        // ---- staging, transposed [ch][t] (global reads 64B-coalesced) ----
        for (int idx = tid; idx < TCH * 16; idx += 256) {
            int t = idx >> 4, j = idx & 15;
            size_t tok = (size_t)(b * LSEQ + c0 + t);
            sdtT[j][t] = dtg[tok * DINNER + dg * 16 + j];
            suT [j][t] = u  [tok * DINNER + dg * 16 + j];
            szT [j][t] = xz [tok * 768 + DINNER + dg * 16 + j];
            sBT [j][t] = bc [tok * 32 + j];
            sCT [j][t] = bc [tok * 32 + 16 + j];
        }
        __syncthreads();

        // ---- serial scan, 4 t-steps per float4 read ----
        for (int t4 = 0; t4 < TCH - 1; t4 += 4) {
            float4 dt4 = *(const float4*)&sdtT[dch][t4];
            float4 u4  = *(const float4*)&suT [dch][t4];
            float4 B4  = *(const float4*)&sBT [s][t4];
            float4 C4  = *(const float4*)&sCT [s][t4];
            SCAN_STEP(dt4.x, u4.x, B4.x, C4.x, t4 + 0)
            SCAN_STEP(dt4.y, u4.y, B4.y, C4.y, t4 + 1)
            SCAN_STEP(dt4.z, u4.z, B4.z, C4.z, t4 + 2)
            SCAN_STEP(dt4.w, u4.w, B4.w, C4.w, t4 + 3)
        }
        {   // tail t = 48
            int t = TCH - 1;
            float dtv = sdtT[dch][t], uv = suT[dch][t];
            float Bv = sBT[s][t],     Cv = sCT[s][t];
            SCAN_STEP(dtv, uv, Bv, Cv, t)
        }
        __syncthreads();

        // ---- epilogue: y = (sum + u*D) * silu(z), coalesced bf16 writes ----
        for (int idx = tid; idx < TCH * 16; idx += 256) {
            int t = idx >> 4, c = idx & 15;
            float sum = sy[t][c];
            float uv = suT[c][t];
            float zv = szT[c][t];
            float sig = 1.f / (1.f + __expf(-zv));
            y[(size_t)(b * LSEQ + c0 + t) * DINNER + dg * 16 + c] =
                __float2bfloat16((sum + uv * Dd) * (zv * sig));
        }
        __syncthreads();
    }
#undef SCAN_STEP
}

// ---------------------------------------------------------------------------
extern "C" void kernel_launch(void* const* d_in, const int* in_sizes, int n_in,
                              void* d_out, int out_size, void* d_ws, size_t ws_size,
                              hipStream_t stream)
{
    const float* x         = (const float*)d_in[0];
    const float* pe_w      = (const float*)d_in[1];
    const float* pe_b      = (const float*)d_in[2];
    const float* norm_w    = (const float*)d_in[3];
    const float* norm_b    = (const float*)d_in[4];
    const float* in_proj_w = (const float*)d_in[5];
    const float* conv_w    = (const float*)d_in[6];
    const float* conv_b    = (const float*)d_in[7];
    const float* xproj_w   = (const float*)d_in[8];
    const float* dtproj_w  = (const float*)d_in[9];
    const float* dtproj_b  = (const float*)d_in[10];
    const float* A_log     = (const float*)d_in[11];
    const float* D_param   = (const float*)d_in[12];
    const float* outproj_w = (const float*)d_in[13];
    const float* normf_w   = (const float*)d_in[14];
    const float* normf_b   = (const float*)d_in[15];

    float* ws = (float*)d_ws;
    float* residual = ws;                       // 301056 f32
    float* xz       = residual + 301056;        // 1204224 f32
    float* ubuf     = xz + 1204224;             // 602112 f32
    float* dtbuf    = ubuf + 602112;            // 602112 f32
    float* bcbuf    = dtbuf + 602112;           // 50176 f32
    __hip_bfloat16* hn      = (__hip_bfloat16*)(ws + 2759680);  // 301056 bf16
    __hip_bfloat16* ybf     = (__hip_bfloat16*)(ws + 2910208);  // 602112 bf16
    __hip_bfloat16* patches = (__hip_bfloat16*)(ws + 3211264);  // 1204224 bf16
    short* w_in  = (short*)(ws + 3813376);      // 3538944 bf16
    short* w_out = (short*)(ws + 5582848);      // 1769472 bf16
    short* w_pe  = (short*)(ws + 6467584);      // 147456 bf16
    float* xpwT  = ws + 6541312;                // 405504 f32
    float* dtwT  = xpwT + 405504;               // 110592 f32

    prep<<<12048, 256, 0, stream>>>(
        in_proj_w, outproj_w, pe_w, xproj_w, dtproj_w, x,
        w_in, w_out, w_pe, xpwT, dtwT, patches);
    gemm_ln<768><<<98, 256, 0, stream>>>(
        patches, w_pe, pe_b, residual, hn, nullptr, norm_w, norm_b, 0);

    for (int i = 0; i < DEPTH; ++i) {
        int last = (i == DEPTH - 1);
        gemm_in<192><<<dim3(25, 12), 256, 0, stream>>>(
            hn, w_in + (size_t)i * 768 * DMODEL, xz, NTOK, 768);
        conv_xproj_dt<<<392, 256, 0, stream>>>(
            xz, conv_w + (size_t)i * DINNER * 4, conv_b + (size_t)i * DINNER,
            xpwT + (size_t)i * 384 * 44, dtwT + (size_t)i * 12 * 384,
            dtproj_b + (size_t)i * DINNER, ubuf, dtbuf, bcbuf);
        scan_kernel<<<192, 256, 0, stream>>>(
            ubuf, dtbuf, bcbuf, xz, A_log + (size_t)i * DINNER * DSTATE,
            D_param + (size_t)i * DINNER, ybf);
        gemm_ln<384><<<98, 256, 0, stream>>>(
            ybf, w_out + (size_t)i * DMODEL * DINNER, nullptr, residual, hn,
            last ? (float*)d_out : nullptr,
            last ? normf_w : norm_w + (i + 1) * DMODEL,
            last ? normf_b : norm_b + (i + 1) * DMODEL,
            1);
    }
}

// Round 8
// 1542.483 us; speedup vs baseline: 1.7706x; 1.0472x over previous
//
#include <hip/hip_runtime.h>
#include <hip/hip_bf16.h>

// ---------------------------------------------------------------------------
// VisionMamba, round 19: R18 scan core (transposed LDS + DPP rowsum) with
// R12-style float4 global staging + in-LDS transpose. Pipeline otherwise
// identical to R12 (1421us verified).
// B=8, L=196, D_MODEL=192, D_INNER=384, D_STATE=16, DT_RANK=12, DEPTH=24.
//
// Evidence: R17 probes: scan=13.8us biggest kernel (gi~5, cv~8, gl~4.5,
// gaps~26/layer). R18 (transposed scan, DPP): scan 13.8->22us REGRESSION;
// only staging changed from float4 (15 wave-inst/chunk) to scalar (61
// wave-inst/chunk) at ~1 wave/SIMD -> exposed-latency staging is the prime
// suspect; DPP core arithmetic checks out (~2.6us). This round: SINGLE
// change vs R18 = staging back to 196-thread float4 reads + 20 ds_write_b32
// transpose scatter (2-way bank aliasing = free). If wall >=1500, the DPP
// core is guilty -> revert scan wholesale next round.
// ---------------------------------------------------------------------------

#define NTOK   1568   // B * L
#define DMODEL 192
#define DINNER 384
#define DSTATE 16
#define DTRANK 12
#define DEPTH  24
#define LSEQ   196
#define TCH    49     // scan time-chunk (196 = 4*49)
#define TPAD   52     // padded t-stride (52 f32 = 208 B; 16B-aligned)
#define LDA    40     // LDS row stride in bf16 elements (80B)

typedef __attribute__((ext_vector_type(8))) short short8;
typedef __attribute__((ext_vector_type(4))) short short4v;
typedef __attribute__((ext_vector_type(4))) float floatx4;

__device__ inline short f2bf(float f) {
    __hip_bfloat16 h = __float2bfloat16(f);
    return *reinterpret_cast<short*>(&h);
}

// 16-lane (DPP row) sum: every lane of each 16-lane row ends with the row sum.
// xor1/xor2 via quad_perm, then row_ror:4 + row_ror:8. Pure VALU, no DS pipe.
__device__ __forceinline__ float rowsum16(float x) {
    float v = x;
    int i;
    i = __builtin_amdgcn_mov_dpp(__float_as_int(v), 0xB1, 0xf, 0xf, false);  // quad_perm [1,0,3,2]
    v += __int_as_float(i);
    i = __builtin_amdgcn_mov_dpp(__float_as_int(v), 0x4E, 0xf, 0xf, false);  // quad_perm [2,3,0,1]
    v += __int_as_float(i);
    i = __builtin_amdgcn_mov_dpp(__float_as_int(v), 0x124, 0xf, 0xf, false); // row_ror:4
    v += __int_as_float(i);
    i = __builtin_amdgcn_mov_dpp(__float_as_int(v), 0x128, 0xf, 0xf, false); // row_ror:8
    v += __int_as_float(i);
    return v;
}

// ---------------- merged pre-stage: weight cvt + transposes + im2col ----------------
#define PR1 884736
#define PR2 1327104   // +442368
#define PR3 1363968   // +36864
#define PR4 1769472   // +405504
#define PR5 1880064   // +110592
#define PR6 3084288   // +1204224
__global__ __launch_bounds__(256) void prep(
    const float* __restrict__ inw, const float* __restrict__ outw,
    const float* __restrict__ pew, const float* __restrict__ xpw,
    const float* __restrict__ dtw, const float* __restrict__ x,
    short* __restrict__ w_in, short* __restrict__ w_out,
    short* __restrict__ w_pe, float* __restrict__ xpwT,
    float* __restrict__ dtwT, __hip_bfloat16* __restrict__ patches)
{
    int idx = blockIdx.x * 256 + threadIdx.x;
    if (idx < PR3) {
        float4 v; short* dst;
        if (idx < PR1)      { v = ((const float4*)inw)[idx];        dst = w_in  + (size_t)idx * 4; }
        else if (idx < PR2) { int i = idx - PR1; v = ((const float4*)outw)[i]; dst = w_out + (size_t)i * 4; }
        else                { int i = idx - PR2; v = ((const float4*)pew)[i];  dst = w_pe  + (size_t)i * 4; }
        short4v o;
        o[0] = f2bf(v.x); o[1] = f2bf(v.y); o[2] = f2bf(v.z); o[3] = f2bf(v.w);
        *(short4v*)dst = o;
    } else if (idx < PR4) {
        int i = idx - PR3;                    // xpwT[layer][k][e] = xpw[layer][e][k]
        int layer = i / 16896, rem = i % 16896;
        int k = rem / 44, e = rem % 44;
        xpwT[i] = xpw[(size_t)layer * 16896 + e * 384 + k];
    } else if (idx < PR5) {
        int i = idx - PR4;                    // dtwT[layer][r][d] = dtw[layer][d][r]
        int layer = i / 4608, rem = i % 4608;
        int r = rem / 384, d = rem % 384;
        dtwT[i] = dtw[(size_t)layer * 4608 + d * 12 + r];
    } else if (idx < PR6) {
        int i = idx - PR5;                    // im2col
        int tok = i / 768, e = i % 768;
        int b = tok / LSEQ, l = tok % LSEQ;
        int py = l / 14, px = l % 14;
        int ic = e >> 8, rem = e & 255, ky = rem >> 4, kx = rem & 15;
        patches[i] = __float2bfloat16(x[((b * 3 + ic) * 224 + py * 16 + ky) * 224 + px * 16 + kx]);
    }
}

// ---------------- gemm_in: xz[M,768] = hn[M,192] @ W[768,192]^T ----------------
template<int K>
__global__ __launch_bounds__(256) void gemm_in(
    const __hip_bfloat16* __restrict__ A, const short* __restrict__ Wb,
    float* __restrict__ C, int M, int N)
{
    __shared__ short As[64 * LDA];
    __shared__ short Ws[64 * LDA];
    int tid = threadIdx.x;
    int m0 = blockIdx.x * 64, n0 = blockIdx.y * 64;
    int wv = tid >> 6, lane = tid & 63;
    int fm = lane & 15, q = lane >> 4;
    int row = tid >> 2, kc = (tid & 3) * 8;
    const short* Ab = (const short*)A;
    floatx4 acc[4];
#pragma unroll
    for (int nt = 0; nt < 4; ++nt) acc[nt] = (floatx4){0.f, 0.f, 0.f, 0.f};

#pragma unroll
    for (int k0 = 0; k0 < K; k0 += 32) {
        {
            int m = m0 + row;
            short8 v = {0,0,0,0,0,0,0,0};
            if (m < M) v = *(const short8*)&Ab[(size_t)m * K + k0 + kc];
            *(short8*)&As[row * LDA + kc] = v;
        }
        {
            short8 w = *(const short8*)&Wb[(size_t)(n0 + row) * K + k0 + kc];
            *(short8*)&Ws[row * LDA + kc] = w;
        }
        __syncthreads();
        short8 af = *(const short8*)&As[(wv * 16 + fm) * LDA + q * 8];
#pragma unroll
        for (int nt = 0; nt < 4; ++nt) {
            short8 bf = *(const short8*)&Ws[(nt * 16 + fm) * LDA + q * 8];
            acc[nt] = __builtin_amdgcn_mfma_f32_16x16x32_bf16(af, bf, acc[nt], 0, 0, 0);
        }
        __syncthreads();
    }
#pragma unroll
    for (int nt = 0; nt < 4; ++nt) {
        int col = n0 + nt * 16 + fm;
#pragma unroll
        for (int r = 0; r < 4; ++r) {
            int mrow = m0 + wv * 16 + q * 4 + r;
            if (mrow < M) C[(size_t)mrow * N + col] = acc[nt][r];
        }
    }
}

// ---------------- gemm_ln: 16-row tiles, pipelined LDS, fused residual+LN ----------------
template<int K>
__global__ __launch_bounds__(256) void gemm_ln(
    const __hip_bfloat16* __restrict__ A, const short* __restrict__ Wb,
    const float* __restrict__ bias, float* __restrict__ residual,
    __hip_bfloat16* __restrict__ hn, float* __restrict__ outf,
    const float* __restrict__ lnw, const float* __restrict__ lnb,
    int accumulate)
{
    __shared__ short As[16 * LDA];
    __shared__ short Ws[192 * LDA];
    __shared__ float slw[192], slb[192], sbias[192];
    __shared__ float sS1[4][16], sS2[4][16];
    int tid = threadIdx.x;
    int m0 = blockIdx.x * 16;
    int wv = tid >> 6, lane = tid & 63;
    int fm = lane & 15, q = lane >> 4;
    int wrow = tid >> 2, kc = (tid & 3) * 8;
    if (tid < 192) {
        slw[tid] = lnw[tid];
        slb[tid] = lnb[tid];
        sbias[tid] = bias ? bias[tid] : 0.f;
    }
    const short* Ab = (const short*)A;
    floatx4 acc[3];
#pragma unroll
    for (int j = 0; j < 3; ++j) acc[j] = (floatx4){0.f, 0.f, 0.f, 0.f};

    short8 aR = {0,0,0,0,0,0,0,0};
    short8 wR[3];
    if (tid < 64) aR = *(const short8*)&Ab[(size_t)(m0 + (tid >> 2)) * K + kc];
#pragma unroll
    for (int j = 0; j < 3; ++j)
        wR[j] = *(const short8*)&Wb[(size_t)(wrow + 64 * j) * K + kc];

    for (int k0 = 0; k0 < K; k0 += 32) {
        if (tid < 64) *(short8*)&As[(tid >> 2) * LDA + kc] = aR;
#pragma unroll
        for (int j = 0; j < 3; ++j)
            *(short8*)&Ws[(wrow + 64 * j) * LDA + kc] = wR[j];
        __syncthreads();
        int kn = k0 + 32;
        if (kn < K) {
            if (tid < 64) aR = *(const short8*)&Ab[(size_t)(m0 + (tid >> 2)) * K + kn + kc];
#pragma unroll
            for (int j = 0; j < 3; ++j)
                wR[j] = *(const short8*)&Wb[(size_t)(wrow + 64 * j) * K + kn + kc];
        }
        short8 af = *(const short8*)&As[fm * LDA + q * 8];
#pragma unroll
        for (int j = 0; j < 3; ++j) {
            int ct = wv * 3 + j;
            short8 bf = *(const short8*)&Ws[(ct * 16 + fm) * LDA + q * 8];
            acc[j] = __builtin_amdgcn_mfma_f32_16x16x32_bf16(af, bf, acc[j], 0, 0, 0);
        }
        __syncthreads();
    }

    float v[3][4];
#pragma unroll
    for (int r = 0; r < 4; ++r) {
        int m = m0 + q * 4 + r;
#pragma unroll
        for (int j = 0; j < 3; ++j) {
            int col = (wv * 3 + j) * 16 + fm;
            float t = acc[j][r] + sbias[col];
            if (accumulate) t += residual[(size_t)m * DMODEL + col];
            v[j][r] = t;
        }
    }
#pragma unroll
    for (int r = 0; r < 4; ++r) {
        int m = m0 + q * 4 + r;
#pragma unroll
        for (int j = 0; j < 3; ++j)
            residual[(size_t)m * DMODEL + (wv * 3 + j) * 16 + fm] = v[j][r];
    }
#pragma unroll
    for (int r = 0; r < 4; ++r) {
        float s1 = v[0][r] + v[1][r] + v[2][r];
        float s2 = v[0][r]*v[0][r] + v[1][r]*v[1][r] + v[2][r]*v[2][r];
        s1 += __shfl_xor(s1, 1); s2 += __shfl_xor(s2, 1);
        s1 += __shfl_xor(s1, 2); s2 += __shfl_xor(s2, 2);
        s1 += __shfl_xor(s1, 4); s2 += __shfl_xor(s2, 4);
        s1 += __shfl_xor(s1, 8); s2 += __shfl_xor(s2, 8);
        if (fm == 0) { sS1[wv][q * 4 + r] = s1; sS2[wv][q * 4 + r] = s2; }
    }
    __syncthreads();
#pragma unroll
    for (int r = 0; r < 4; ++r) {
        int row = q * 4 + r;
        int m = m0 + row;
        float S1 = sS1[0][row] + sS1[1][row] + sS1[2][row] + sS1[3][row];
        float S2 = sS2[0][row] + sS2[1][row] + sS2[2][row] + sS2[3][row];
        float mean = S1 * (1.f / DMODEL);
        float var  = S2 * (1.f / DMODEL) - mean * mean;
        float rstd = rsqrtf(var + 1e-5f);
#pragma unroll
        for (int j = 0; j < 3; ++j) {
            int col = (wv * 3 + j) * 16 + fm;
            float o = (v[j][r] - mean) * rstd * slw[col] + slb[col];
            if (outf) outf[(size_t)m * DMODEL + col] = o;
            else      hn[(size_t)m * DMODEL + col] = __float2bfloat16(o);
        }
    }
}

// ---------------- conv + silu + x_proj + dt : 4 tokens/block (R12 original) ----------
__global__ __launch_bounds__(256) void conv_xproj_dt(
    const float* __restrict__ xz, const float* __restrict__ cw,
    const float* __restrict__ cb, const float* __restrict__ xpwT,
    const float* __restrict__ dtwT, const float* __restrict__ dtb,
    float* __restrict__ u, float* __restrict__ dtg, float* __restrict__ bcg)
{
    __shared__ float sxz[7 * 384];
    __shared__ float su[4 * 384];
    __shared__ float sx[4 * 48];
    int blk = blockIdx.x;
    int b = blk / 49, c = blk % 49;
    int l0 = c * 4;
    int tid = threadIdx.x;

    for (int idx = tid; idx < 7 * 384; idx += 256) {
        int t = idx / 384, d = idx % 384;
        int l = l0 - 3 + t;
        sxz[idx] = (l >= 0) ? xz[(size_t)(b * LSEQ + l) * 768 + d] : 0.f;
    }
    __syncthreads();

    for (int idx = tid; idx < 4 * 384; idx += 256) {
        int t = idx / 384, d = idx % 384;
        float4 w4 = *(const float4*)&cw[d * 4];
        float acc = cb[d]
            + sxz[t * 384 + d]       * w4.x
            + sxz[(t + 1) * 384 + d] * w4.y
            + sxz[(t + 2) * 384 + d] * w4.z
            + sxz[(t + 3) * 384 + d] * w4.w;
        float sig = 1.f / (1.f + __expf(-acc));
        float val = acc * sig;
        su[idx] = val;
        u[(size_t)(b * LSEQ + l0 + t) * 384 + d] = val;
    }
    __syncthreads();

    {
        int wv = tid >> 6, e = tid & 63;
        if (e < 44) {
            float a0 = 0.f, a1 = 0.f, a2 = 0.f, a3 = 0.f;
            const float* ur = &su[wv * 384];
            for (int j = 0; j < 384; j += 4) {
                a0 += ur[j]     * xpwT[(j    ) * 44 + e];
                a1 += ur[j + 1] * xpwT[(j + 1) * 44 + e];
                a2 += ur[j + 2] * xpwT[(j + 2) * 44 + e];
                a3 += ur[j + 3] * xpwT[(j + 3) * 44 + e];
            }
            sx[wv * 48 + e] = (a0 + a1) + (a2 + a3);
        }
    }
    __syncthreads();

    for (int idx = tid; idx < 4 * 384; idx += 256) {
        int t = idx / 384, d = idx % 384;
        float acc = dtb[d];
#pragma unroll
        for (int r = 0; r < DTRANK; ++r) acc += sx[t * 48 + r] * dtwT[r * 384 + d];
        float sp = (acc > 20.f) ? acc : log1pf(__expf(acc));
        dtg[(size_t)(b * LSEQ + l0 + t) * 384 + d] = sp;
    }
    if (tid < 128) {
        int t = tid >> 5, j = tid & 31;
        bcg[(size_t)(b * LSEQ + l0 + t) * 32 + j] = sx[t * 48 + 12 + j];
    }
}

// ---------------- selective scan: float4 staging -> transposed LDS + DPP ----------------
// Staging: 196 threads x 5 float4 global reads (R12 pattern), scattered into
// [ch][t] LDS via 20 ds_write_b32 (2-way bank aliasing = free). Serial loop
// reads 4 t-steps per float4 (row-broadcast); DPP rowsum16 contracts over s.
__global__ __launch_bounds__(256) void scan_kernel(
    const float* __restrict__ u, const float* __restrict__ dtg,
    const float* __restrict__ bc, const float* __restrict__ xz,
    const float* __restrict__ Alog, const float* __restrict__ Dp,
    __hip_bfloat16* __restrict__ y)
{
    __shared__ float sdtT[16][TPAD];
    __shared__ float suT [16][TPAD];
    __shared__ float szT [16][TPAD];
    __shared__ float sBT [16][TPAD];
    __shared__ float sCT [16][TPAD];
    __shared__ float sy  [TCH][16];

    int b  = blockIdx.x / 24;
    int dg = blockIdx.x % 24;
    int tid = threadIdx.x;
    int s = tid & 15, dch = tid >> 4;
    float Ads = -expf(Alog[(dg * 16 + dch) * DSTATE + s]);
    float Dd  = Dp[dg * 16 + (tid & 15)];   // epilogue channel = tid&15
    float h = 0.f;

#define SCAN_STEP(dtv, uv, Bv, Cv, tt)                      \
    {                                                       \
        float dA = __expf((dtv) * Ads);                     \
        h = dA * h + ((dtv) * (uv)) * (Bv);                 \
        float p = rowsum16(h * (Cv));                       \
        if (s == 0) sy[tt][dch] = p;                        \
    }

    for (int c0 = 0; c0 < LSEQ; c0 += TCH) {
        // ---- staging: float4 global reads + in-LDS transpose scatter ----
        if (tid < TCH * 4) {
            int t = tid >> 2, j4 = (tid & 3) * 4;
            size_t tok = (size_t)(b * LSEQ + c0 + t);
            float4 d4 = *(const float4*)&dtg[tok * DINNER + dg * 16 + j4];
            float4 u4 = *(const float4*)&u  [tok * DINNER + dg * 16 + j4];
            float4 z4 = *(const float4*)&xz [tok * 768 + DINNER + dg * 16 + j4];
            float4 B4 = *(const float4*)&bc [tok * 32 + j4];
            float4 C4 = *(const float4*)&bc [tok * 32 + 16 + j4];
            sdtT[j4 + 0][t] = d4.x; sdtT[j4 + 1][t] = d4.y;
            sdtT[j4 + 2][t] = d4.z; sdtT[j4 + 3][t] = d4.w;
            suT [j4 + 0][t] = u4.x; suT [j4 + 1][t] = u4.y;
            suT [j4 + 2][t] = u4.z; suT [j4 + 3][t] = u4.w;
            szT [j4 + 0][t] = z4.x; szT [j4 + 1][t] = z4.y;
            szT [j4 + 2][t] = z4.z; szT [j4 + 3][t] = z4.w;
            sBT [j4 + 0][t] = B4.x; sBT [j4 + 1][t] = B4.y;
            sBT [j4 + 2][t] = B4.z; sBT [j4 + 3][t] = B4.w;
            sCT [j4 + 0][t] = C4.x; sCT [j4 + 1][t] = C4.y;
            sCT [j4 + 2][t] = C4.z; sCT [j4 + 3][t] = C4.w;
        }
        __syncthreads();

        // ---- serial scan, 4 t-steps per float4 read ----
        for (int t4 = 0; t4 < TCH - 1; t4 += 4) {
            float4 dt4 = *(const float4*)&sdtT[dch][t4];
            float4 u4  = *(const float4*)&suT [dch][t4];
            float4 B4  = *(const float4*)&sBT [s][t4];
            float4 C4  = *(const float4*)&sCT [s][t4];
            SCAN_STEP(dt4.x, u4.x, B4.x, C4.x, t4 + 0)
            SCAN_STEP(dt4.y, u4.y, B4.y, C4.y, t4 + 1)
            SCAN_STEP(dt4.z, u4.z, B4.z, C4.z, t4 + 2)
            SCAN_STEP(dt4.w, u4.w, B4.w, C4.w, t4 + 3)
        }
        {   // tail t = 48
            int t = TCH - 1;
            float dtv = sdtT[dch][t], uv = suT[dch][t];
            float Bv = sBT[s][t],     Cv = sCT[s][t];
            SCAN_STEP(dtv, uv, Bv, Cv, t)
        }
        __syncthreads();

        // ---- epilogue: y = (sum + u*D) * silu(z), coalesced bf16 writes ----
        for (int idx = tid; idx < TCH * 16; idx += 256) {
            int t = idx >> 4, c = idx & 15;
            float sum = sy[t][c];
            float uv = suT[c][t];
            float zv = szT[c][t];
            float sig = 1.f / (1.f + __expf(-zv));
            y[(size_t)(b * LSEQ + c0 + t) * DINNER + dg * 16 + c] =
                __float2bfloat16((sum + uv * Dd) * (zv * sig));
        }
        __syncthreads();
    }
#undef SCAN_STEP
}

// ---------------------------------------------------------------------------
extern "C" void kernel_launch(void* const* d_in, const int* in_sizes, int n_in,
                              void* d_out, int out_size, void* d_ws, size_t ws_size,
                              hipStream_t stream)
{
    const float* x         = (const float*)d_in[0];
    const float* pe_w      = (const float*)d_in[1];
    const float* pe_b      = (const float*)d_in[2];
    const float* norm_w    = (const float*)d_in[3];
    const float* norm_b    = (const float*)d_in[4];
    const float* in_proj_w = (const float*)d_in[5];
    const float* conv_w    = (const float*)d_in[6];
    const float* conv_b    = (const float*)d_in[7];
    const float* xproj_w   = (const float*)d_in[8];
    const float* dtproj_w  = (const float*)d_in[9];
    const float* dtproj_b  = (const float*)d_in[10];
    const float* A_log     = (const float*)d_in[11];
    const float* D_param   = (const float*)d_in[12];
    const float* outproj_w = (const float*)d_in[13];
    const float* normf_w   = (const float*)d_in[14];
    const float* normf_b   = (const float*)d_in[15];

    float* ws = (float*)d_ws;
    float* residual = ws;                       // 301056 f32
    float* xz       = residual + 301056;        // 1204224 f32
    float* ubuf     = xz + 1204224;             // 602112 f32
    float* dtbuf    = ubuf + 602112;            // 602112 f32
    float* bcbuf    = dtbuf + 602112;           // 50176 f32
    __hip_bfloat16* hn      = (__hip_bfloat16*)(ws + 2759680);  // 301056 bf16
    __hip_bfloat16* ybf     = (__hip_bfloat16*)(ws + 2910208);  // 602112 bf16
    __hip_bfloat16* patches = (__hip_bfloat16*)(ws + 3211264);  // 1204224 bf16
    short* w_in  = (short*)(ws + 3813376);      // 3538944 bf16
    short* w_out = (short*)(ws + 5582848);      // 1769472 bf16
    short* w_pe  = (short*)(ws + 6467584);      // 147456 bf16
    float* xpwT  = ws + 6541312;                // 405504 f32
    float* dtwT  = xpwT + 405504;               // 110592 f32

    prep<<<12048, 256, 0, stream>>>(
        in_proj_w, outproj_w, pe_w, xproj_w, dtproj_w, x,
        w_in, w_out, w_pe, xpwT, dtwT, patches);
    gemm_ln<768><<<98, 256, 0, stream>>>(
        patches, w_pe, pe_b, residual, hn, nullptr, norm_w, norm_b, 0);

    for (int i = 0; i < DEPTH; ++i) {
        int last = (i == DEPTH - 1);
        gemm_in<192><<<dim3(25, 12), 256, 0, stream>>>(
            hn, w_in + (size_t)i * 768 * DMODEL, xz, NTOK, 768);
        conv_xproj_dt<<<392, 256, 0, stream>>>(
            xz, conv_w + (size_t)i * DINNER * 4, conv_b + (size_t)i * DINNER,
            xpwT + (size_t)i * 384 * 44, dtwT + (size_t)i * 12 * 384,
            dtproj_b + (size_t)i * DINNER, ubuf, dtbuf, bcbuf);
        scan_kernel<<<192, 256, 0, stream>>>(
            ubuf, dtbuf, bcbuf, xz, A_log + (size_t)i * DINNER * DSTATE,
            D_param + (size_t)i * DINNER, ybf);
        gemm_ln<384><<<98, 256, 0, stream>>>(
            ybf, w_out + (size_t)i * DMODEL * DINNER, nullptr, residual, hn,
            last ? (float*)d_out : nullptr,
            last ? normf_w : norm_w + (i + 1) * DMODEL,
            last ? normf_b : norm_b + (i + 1) * DMODEL,
            1);
    }
}

// Round 9
// 1469.669 us; speedup vs baseline: 1.8583x; 1.0495x over previous
//
#include <hip/hip_runtime.h>
#include <hip/hip_bf16.h>

// ---------------------------------------------------------------------------
// VisionMamba, round 20: R12 pipeline with gemm_ln(i) + gemm_in(i+1) FUSED.
// B=8, L=196, D_MODEL=192, D_INNER=384, D_STATE=16, DT_RANK=12, DEPTH=24.
//
// Evidence: R17 probes: kernels ~31us/layer (gi 5, cv 8, sc 13.8, gl 4.5),
// gaps ~26us/layer. R18/R19 scan rewrites regressed (+5..8/layer) -> scan
// reverted to R12 exact. R13/R14 persistent kernels regressed. This round
// attacks gaps by dispatch-count reduction with verified bodies: gemm_ln's
// block already holds the 16 normalized rows gemm_in(i+1) needs. Write hn
// to an LDS bf16 tile (same rounding as the old global hn) and run the
// next in_proj (M=16,N=768,K=192) in-block: af from LDS (gemm_ln's verified
// fm-row pattern), bf DIRECT from global w_in (the exact rows Ws was staged
// from), C-write = gemm_in's verified scatter. hn global round-trip gone;
// dispatches 98 -> 74 (4 -> 3 per layer).
// ---------------------------------------------------------------------------

#define NTOK   1568   // B * L
#define DMODEL 192
#define DINNER 384
#define DSTATE 16
#define DTRANK 12
#define DEPTH  24
#define LSEQ   196
#define TCH    49     // scan time-chunk (196 = 4*49)
#define LDA    40     // LDS row stride in bf16 elements (80B)
#define ALD2   200    // hn LDS tile row stride (192 + 8 pad, bf16)

typedef __attribute__((ext_vector_type(8))) short short8;
typedef __attribute__((ext_vector_type(4))) short short4v;
typedef __attribute__((ext_vector_type(4))) float floatx4;

__device__ inline short f2bf(float f) {
    __hip_bfloat16 h = __float2bfloat16(f);
    return *reinterpret_cast<short*>(&h);
}

// ---------------- merged pre-stage: weight cvt + transposes + im2col ----------------
#define PR1 884736
#define PR2 1327104   // +442368
#define PR3 1363968   // +36864
#define PR4 1769472   // +405504
#define PR5 1880064   // +110592
#define PR6 3084288   // +1204224
__global__ __launch_bounds__(256) void prep(
    const float* __restrict__ inw, const float* __restrict__ outw,
    const float* __restrict__ pew, const float* __restrict__ xpw,
    const float* __restrict__ dtw, const float* __restrict__ x,
    short* __restrict__ w_in, short* __restrict__ w_out,
    short* __restrict__ w_pe, float* __restrict__ xpwT,
    float* __restrict__ dtwT, __hip_bfloat16* __restrict__ patches)
{
    int idx = blockIdx.x * 256 + threadIdx.x;
    if (idx < PR3) {
        float4 v; short* dst;
        if (idx < PR1)      { v = ((const float4*)inw)[idx];        dst = w_in  + (size_t)idx * 4; }
        else if (idx < PR2) { int i = idx - PR1; v = ((const float4*)outw)[i]; dst = w_out + (size_t)i * 4; }
        else                { int i = idx - PR2; v = ((const float4*)pew)[i];  dst = w_pe  + (size_t)i * 4; }
        short4v o;
        o[0] = f2bf(v.x); o[1] = f2bf(v.y); o[2] = f2bf(v.z); o[3] = f2bf(v.w);
        *(short4v*)dst = o;
    } else if (idx < PR4) {
        int i = idx - PR3;                    // xpwT[layer][k][e] = xpw[layer][e][k]
        int layer = i / 16896, rem = i % 16896;
        int k = rem / 44, e = rem % 44;
        xpwT[i] = xpw[(size_t)layer * 16896 + e * 384 + k];
    } else if (idx < PR5) {
        int i = idx - PR4;                    // dtwT[layer][r][d] = dtw[layer][d][r]
        int layer = i / 4608, rem = i % 4608;
        int r = rem / 384, d = rem % 384;
        dtwT[i] = dtw[(size_t)layer * 4608 + d * 12 + r];
    } else if (idx < PR6) {
        int i = idx - PR5;                    // im2col
        int tok = i / 768, e = i % 768;
        int b = tok / LSEQ, l = tok % LSEQ;
        int py = l / 14, px = l % 14;
        int ic = e >> 8, rem = e & 255, ky = rem >> 4, kx = rem & 15;
        patches[i] = __float2bfloat16(x[((b * 3 + ic) * 224 + py * 16 + ky) * 224 + px * 16 + kx]);
    }
}

// ---------------- fused gemm_ln + next-layer gemm_in ----------------
// Body = verified gemm_ln (16-row tiles, pipelined LDS, residual+LN), except
// the normalized rows go to LDS tile hnT (bf16, same rounding as old global
// hn). Then in-block in_proj: M=16 x N=768 x K=192; af from hnT (gemm_ln's
// fm-row fragment pattern), bf direct from global w_in (rows Ws was staged
// from), C-scatter = gemm_in's verified pattern.
template<int K>
__global__ __launch_bounds__(256) void gemm_ln_in(
    const __hip_bfloat16* __restrict__ A, const short* __restrict__ Wb,
    const float* __restrict__ bias, float* __restrict__ residual,
    const float* __restrict__ lnw, const float* __restrict__ lnb,
    int accumulate, const short* __restrict__ win, float* __restrict__ xz)
{
    __shared__ short As[16 * LDA];
    __shared__ short Ws[192 * LDA];
    __shared__ short hnT[16 * ALD2];
    __shared__ float slw[192], slb[192], sbias[192];
    __shared__ float sS1[4][16], sS2[4][16];
    int tid = threadIdx.x;
    int m0 = blockIdx.x * 16;
    int wv = tid >> 6, lane = tid & 63;
    int fm = lane & 15, q = lane >> 4;
    int wrow = tid >> 2, kc = (tid & 3) * 8;
    if (tid < 192) {
        slw[tid] = lnw[tid];
        slb[tid] = lnb[tid];
        sbias[tid] = bias ? bias[tid] : 0.f;
    }
    const short* Ab = (const short*)A;
    floatx4 acc[3];
#pragma unroll
    for (int j = 0; j < 3; ++j) acc[j] = (floatx4){0.f, 0.f, 0.f, 0.f};

    short8 aR = {0,0,0,0,0,0,0,0};
    short8 wR[3];
    if (tid < 64) aR = *(const short8*)&Ab[(size_t)(m0 + (tid >> 2)) * K + kc];
#pragma unroll
    for (int j = 0; j < 3; ++j)
        wR[j] = *(const short8*)&Wb[(size_t)(wrow + 64 * j) * K + kc];

    for (int k0 = 0; k0 < K; k0 += 32) {
        if (tid < 64) *(short8*)&As[(tid >> 2) * LDA + kc] = aR;
#pragma unroll
        for (int j = 0; j < 3; ++j)
            *(short8*)&Ws[(wrow + 64 * j) * LDA + kc] = wR[j];
        __syncthreads();
        int kn = k0 + 32;
        if (kn < K) {
            if (tid < 64) aR = *(const short8*)&Ab[(size_t)(m0 + (tid >> 2)) * K + kn + kc];
#pragma unroll
            for (int j = 0; j < 3; ++j)
                wR[j] = *(const short8*)&Wb[(size_t)(wrow + 64 * j) * K + kn + kc];
        }
        short8 af = *(const short8*)&As[fm * LDA + q * 8];
#pragma unroll
        for (int j = 0; j < 3; ++j) {
            int ct = wv * 3 + j;
            short8 bf = *(const short8*)&Ws[(ct * 16 + fm) * LDA + q * 8];
            acc[j] = __builtin_amdgcn_mfma_f32_16x16x32_bf16(af, bf, acc[j], 0, 0, 0);
        }
        __syncthreads();
    }

    float v[3][4];
#pragma unroll
    for (int r = 0; r < 4; ++r) {
        int m = m0 + q * 4 + r;
#pragma unroll
        for (int j = 0; j < 3; ++j) {
            int col = (wv * 3 + j) * 16 + fm;
            float t = acc[j][r] + sbias[col];
            if (accumulate) t += residual[(size_t)m * DMODEL + col];
            v[j][r] = t;
        }
    }
#pragma unroll
    for (int r = 0; r < 4; ++r) {
        int m = m0 + q * 4 + r;
#pragma unroll
        for (int j = 0; j < 3; ++j)
            residual[(size_t)m * DMODEL + (wv * 3 + j) * 16 + fm] = v[j][r];
    }
#pragma unroll
    for (int r = 0; r < 4; ++r) {
        float s1 = v[0][r] + v[1][r] + v[2][r];
        float s2 = v[0][r]*v[0][r] + v[1][r]*v[1][r] + v[2][r]*v[2][r];
        s1 += __shfl_xor(s1, 1); s2 += __shfl_xor(s2, 1);
        s1 += __shfl_xor(s1, 2); s2 += __shfl_xor(s2, 2);
        s1 += __shfl_xor(s1, 4); s2 += __shfl_xor(s2, 4);
        s1 += __shfl_xor(s1, 8); s2 += __shfl_xor(s2, 8);
        if (fm == 0) { sS1[wv][q * 4 + r] = s1; sS2[wv][q * 4 + r] = s2; }
    }
    __syncthreads();
#pragma unroll
    for (int r = 0; r < 4; ++r) {
        int row = q * 4 + r;
        float S1 = sS1[0][row] + sS1[1][row] + sS1[2][row] + sS1[3][row];
        float S2 = sS2[0][row] + sS2[1][row] + sS2[2][row] + sS2[3][row];
        float mean = S1 * (1.f / DMODEL);
        float var  = S2 * (1.f / DMODEL) - mean * mean;
        float rstd = rsqrtf(var + 1e-5f);
#pragma unroll
        for (int j = 0; j < 3; ++j) {
            int col = (wv * 3 + j) * 16 + fm;
            float o = (v[j][r] - mean) * rstd * slw[col] + slb[col];
            hnT[row * ALD2 + col] = f2bf(o);
        }
    }
    __syncthreads();

    // ---- fused next-layer in_proj: xz[m0..m0+16][768] = hnT @ win^T ----
    floatx4 acc2[12];
#pragma unroll
    for (int j = 0; j < 12; ++j) acc2[j] = (floatx4){0.f, 0.f, 0.f, 0.f};
#pragma unroll
    for (int k0 = 0; k0 < DMODEL; k0 += 32) {
        short8 af = *(const short8*)&hnT[fm * ALD2 + k0 + q * 8];
#pragma unroll
        for (int j = 0; j < 12; ++j) {
            int ct = wv * 12 + j;
            short8 bf = *(const short8*)&win[(size_t)(ct * 16 + fm) * DMODEL + k0 + q * 8];
            acc2[j] = __builtin_amdgcn_mfma_f32_16x16x32_bf16(af, bf, acc2[j], 0, 0, 0);
        }
    }
#pragma unroll
    for (int j = 0; j < 12; ++j) {
        int col = (wv * 12 + j) * 16 + fm;
#pragma unroll
        for (int r = 0; r < 4; ++r)
            xz[(size_t)(m0 + q * 4 + r) * 768 + col] = acc2[j][r];
    }
}

// ---------------- final gemm_ln (last layer: out_proj + residual + final LN) --------
template<int K>
__global__ __launch_bounds__(256) void gemm_ln(
    const __hip_bfloat16* __restrict__ A, const short* __restrict__ Wb,
    const float* __restrict__ bias, float* __restrict__ residual,
    __hip_bfloat16* __restrict__ hn, float* __restrict__ outf,
    const float* __restrict__ lnw, const float* __restrict__ lnb,
    int accumulate)
{
    __shared__ short As[16 * LDA];
    __shared__ short Ws[192 * LDA];
    __shared__ float slw[192], slb[192], sbias[192];
    __shared__ float sS1[4][16], sS2[4][16];
    int tid = threadIdx.x;
    int m0 = blockIdx.x * 16;
    int wv = tid >> 6, lane = tid & 63;
    int fm = lane & 15, q = lane >> 4;
    int wrow = tid >> 2, kc = (tid & 3) * 8;
    if (tid < 192) {
        slw[tid] = lnw[tid];
        slb[tid] = lnb[tid];
        sbias[tid] = bias ? bias[tid] : 0.f;
    }
    const short* Ab = (const short*)A;
    floatx4 acc[3];
#pragma unroll
    for (int j = 0; j < 3; ++j) acc[j] = (floatx4){0.f, 0.f, 0.f, 0.f};

    short8 aR = {0,0,0,0,0,0,0,0};
    short8 wR[3];
    if (tid < 64) aR = *(const short8*)&Ab[(size_t)(m0 + (tid >> 2)) * K + kc];
#pragma unroll
    for (int j = 0; j < 3; ++j)
        wR[j] = *(const short8*)&Wb[(size_t)(wrow + 64 * j) * K + kc];

    for (int k0 = 0; k0 < K; k0 += 32) {
        if (tid < 64) *(short8*)&As[(tid >> 2) * LDA + kc] = aR;
#pragma unroll
        for (int j = 0; j < 3; ++j)
            *(short8*)&Ws[(wrow + 64 * j) * LDA + kc] = wR[j];
        __syncthreads();
        int kn = k0 + 32;
        if (kn < K) {
            if (tid < 64) aR = *(const short8*)&Ab[(size_t)(m0 + (tid >> 2)) * K + kn + kc];
#pragma unroll
            for (int j = 0; j < 3; ++j)
                wR[j] = *(const short8*)&Wb[(size_t)(wrow + 64 * j) * K + kn + kc];
        }
        short8 af = *(const short8*)&As[fm * LDA + q * 8];
#pragma unroll
        for (int j = 0; j < 3; ++j) {
            int ct = wv * 3 + j;
            short8 bf = *(const short8*)&Ws[(ct * 16 + fm) * LDA + q * 8];
            acc[j] = __builtin_amdgcn_mfma_f32_16x16x32_bf16(af, bf, acc[j], 0, 0, 0);
        }
        __syncthreads();
    }

    float v[3][4];
#pragma unroll
    for (int r = 0; r < 4; ++r) {
        int m = m0 + q * 4 + r;
#pragma unroll
        for (int j = 0; j < 3; ++j) {
            int col = (wv * 3 + j) * 16 + fm;
            float t = acc[j][r] + sbias[col];
            if (accumulate) t += residual[(size_t)m * DMODEL + col];
            v[j][r] = t;
        }
    }
#pragma unroll
    for (int r = 0; r < 4; ++r) {
        int m = m0 + q * 4 + r;
#pragma unroll
        for (int j = 0; j < 3; ++j)
            residual[(size_t)m * DMODEL + (wv * 3 + j) * 16 + fm] = v[j][r];
    }
#pragma unroll
    for (int r = 0; r < 4; ++r) {
        float s1 = v[0][r] + v[1][r] + v[2][r];
        float s2 = v[0][r]*v[0][r] + v[1][r]*v[1][r] + v[2][r]*v[2][r];
        s1 += __shfl_xor(s1, 1); s2 += __shfl_xor(s2, 1);
        s1 += __shfl_xor(s1, 2); s2 += __shfl_xor(s2, 2);
        s1 += __shfl_xor(s1, 4); s2 += __shfl_xor(s2, 4);
        s1 += __shfl_xor(s1, 8); s2 += __shfl_xor(s2, 8);
        if (fm == 0) { sS1[wv][q * 4 + r] = s1; sS2[wv][q * 4 + r] = s2; }
    }
    __syncthreads();
#pragma unroll
    for (int r = 0; r < 4; ++r) {
        int row = q * 4 + r;
        int m = m0 + row;
        float S1 = sS1[0][row] + sS1[1][row] + sS1[2][row] + sS1[3][row];
        float S2 = sS2[0][row] + sS2[1][row] + sS2[2][row] + sS2[3][row];
        float mean = S1 * (1.f / DMODEL);
        float var  = S2 * (1.f / DMODEL) - mean * mean;
        float rstd = rsqrtf(var + 1e-5f);
#pragma unroll
        for (int j = 0; j < 3; ++j) {
            int col = (wv * 3 + j) * 16 + fm;
            float o = (v[j][r] - mean) * rstd * slw[col] + slb[col];
            if (outf) outf[(size_t)m * DMODEL + col] = o;
            else      hn[(size_t)m * DMODEL + col] = __float2bfloat16(o);
        }
    }
}

// ---------------- conv + silu + x_proj + dt : 4 tokens/block (R12 original) ----------
__global__ __launch_bounds__(256) void conv_xproj_dt(
    const float* __restrict__ xz, const float* __restrict__ cw,
    const float* __restrict__ cb, const float* __restrict__ xpwT,
    const float* __restrict__ dtwT, const float* __restrict__ dtb,
    float* __restrict__ u, float* __restrict__ dtg, float* __restrict__ bcg)
{
    __shared__ float sxz[7 * 384];
    __shared__ float su[4 * 384];
    __shared__ float sx[4 * 48];
    int blk = blockIdx.x;
    int b = blk / 49, c = blk % 49;
    int l0 = c * 4;
    int tid = threadIdx.x;

    for (int idx = tid; idx < 7 * 384; idx += 256) {
        int t = idx / 384, d = idx % 384;
        int l = l0 - 3 + t;
        sxz[idx] = (l >= 0) ? xz[(size_t)(b * LSEQ + l) * 768 + d] : 0.f;
    }
    __syncthreads();

    for (int idx = tid; idx < 4 * 384; idx += 256) {
        int t = idx / 384, d = idx % 384;
        float4 w4 = *(const float4*)&cw[d * 4];
        float acc = cb[d]
            + sxz[t * 384 + d]       * w4.x
            + sxz[(t + 1) * 384 + d] * w4.y
            + sxz[(t + 2) * 384 + d] * w4.z
            + sxz[(t + 3) * 384 + d] * w4.w;
        float sig = 1.f / (1.f + __expf(-acc));
        float val = acc * sig;
        su[idx] = val;
        u[(size_t)(b * LSEQ + l0 + t) * 384 + d] = val;
    }
    __syncthreads();

    {
        int wv = tid >> 6, e = tid & 63;
        if (e < 44) {
            float a0 = 0.f, a1 = 0.f, a2 = 0.f, a3 = 0.f;
            const float* ur = &su[wv * 384];
            for (int j = 0; j < 384; j += 4) {
                a0 += ur[j]     * xpwT[(j    ) * 44 + e];
                a1 += ur[j + 1] * xpwT[(j + 1) * 44 + e];
                a2 += ur[j + 2] * xpwT[(j + 2) * 44 + e];
                a3 += ur[j + 3] * xpwT[(j + 3) * 44 + e];
            }
            sx[wv * 48 + e] = (a0 + a1) + (a2 + a3);
        }
    }
    __syncthreads();

    for (int idx = tid; idx < 4 * 384; idx += 256) {
        int t = idx / 384, d = idx % 384;
        float acc = dtb[d];
#pragma unroll
        for (int r = 0; r < DTRANK; ++r) acc += sx[t * 48 + r] * dtwT[r * 384 + d];
        float sp = (acc > 20.f) ? acc : log1pf(__expf(acc));
        dtg[(size_t)(b * LSEQ + l0 + t) * 384 + d] = sp;
    }
    if (tid < 128) {
        int t = tid >> 5, j = tid & 31;
        bcg[(size_t)(b * LSEQ + l0 + t) * 32 + j] = sx[t * 48 + 12 + j];
    }
}

// ---------------- selective scan + gating (3-phase, R12 original) ----------------
#define SPAD 272
__global__ __launch_bounds__(256) void scan_kernel(
    const float* __restrict__ u, const float* __restrict__ dtg,
    const float* __restrict__ bc, const float* __restrict__ xz,
    const float* __restrict__ Alog, const float* __restrict__ Dp,
    __hip_bfloat16* __restrict__ y)
{
    __shared__ float sdt[TCH][16];
    __shared__ float su_[TCH][16];
    __shared__ float sz_[TCH][16];
    __shared__ float sB_[TCH][16];
    __shared__ float sC_[TCH][16];
    __shared__ float sprod[TCH][SPAD];

    int b  = blockIdx.x / 24;
    int dg = blockIdx.x % 24;
    int tid = threadIdx.x;
    int s = tid & 15, dl = tid >> 4;
    int d = dg * 16 + dl;
    float Ads = -expf(Alog[d * DSTATE + s]);
    float Dd2 = Dp[dg * 16 + (tid & 15)];
    float h = 0.f;

    for (int c0 = 0; c0 < LSEQ; c0 += TCH) {
        if (tid < TCH * 4) {
            int t = tid >> 2, j4 = (tid & 3) * 4;
            size_t tok = (size_t)(b * LSEQ + c0 + t);
            *(float4*)&sdt[t][j4] = *(const float4*)&dtg[tok * DINNER + dg * 16 + j4];
            *(float4*)&su_[t][j4] = *(const float4*)&u  [tok * DINNER + dg * 16 + j4];
            *(float4*)&sz_[t][j4] = *(const float4*)&xz [tok * 768 + DINNER + dg * 16 + j4];
            *(float4*)&sB_[t][j4] = *(const float4*)&bc [tok * 32 + j4];
            *(float4*)&sC_[t][j4] = *(const float4*)&bc [tok * 32 + 16 + j4];
        }
        __syncthreads();

#pragma unroll 7
        for (int t = 0; t < TCH; ++t) {
            float dtv = sdt[t][dl];
            float uv  = su_[t][dl];
            float Bv  = sB_[t][s];
            float Cv  = sC_[t][s];
            float dA  = __expf(dtv * Ads);
            h = dA * h + (dtv * uv) * Bv;
            sprod[t][dl * 17 + s] = h * Cv;
        }
        __syncthreads();

        for (int i = tid; i < TCH * 16; i += 256) {
            int t = i >> 4, dl2 = i & 15;
            float sum = 0.f;
#pragma unroll
            for (int j = 0; j < 16; ++j) sum += sprod[t][dl2 * 17 + j];
            float uv = su_[t][dl2];
            float zv = sz_[t][dl2];
            float sig = 1.f / (1.f + __expf(-zv));
            y[(size_t)(b * LSEQ + c0 + t) * DINNER + dg * 16 + dl2] =
                __float2bfloat16((sum + uv * Dd2) * (zv * sig));
        }
        __syncthreads();
    }
}

// ---------------------------------------------------------------------------
extern "C" void kernel_launch(void* const* d_in, const int* in_sizes, int n_in,
                              void* d_out, int out_size, void* d_ws, size_t ws_size,
                              hipStream_t stream)
{
    const float* x         = (const float*)d_in[0];
    const float* pe_w      = (const float*)d_in[1];
    const float* pe_b      = (const float*)d_in[2];
    const float* norm_w    = (const float*)d_in[3];
    const float* norm_b    = (const float*)d_in[4];
    const float* in_proj_w = (const float*)d_in[5];
    const float* conv_w    = (const float*)d_in[6];
    const float* conv_b    = (const float*)d_in[7];
    const float* xproj_w   = (const float*)d_in[8];
    const float* dtproj_w  = (const float*)d_in[9];
    const float* dtproj_b  = (const float*)d_in[10];
    const float* A_log     = (const float*)d_in[11];
    const float* D_param   = (const float*)d_in[12];
    const float* outproj_w = (const float*)d_in[13];
    const float* normf_w   = (const float*)d_in[14];
    const float* normf_b   = (const float*)d_in[15];

    float* ws = (float*)d_ws;
    float* residual = ws;                       // 301056 f32
    float* xz       = residual + 301056;        // 1204224 f32
    float* ubuf     = xz + 1204224;             // 602112 f32
    float* dtbuf    = ubuf + 602112;            // 602112 f32
    float* bcbuf    = dtbuf + 602112;           // 50176 f32
    __hip_bfloat16* hn      = (__hip_bfloat16*)(ws + 2759680);  // 301056 bf16 (final-layer sig only)
    __hip_bfloat16* ybf     = (__hip_bfloat16*)(ws + 2910208);  // 602112 bf16
    __hip_bfloat16* patches = (__hip_bfloat16*)(ws + 3211264);  // 1204224 bf16
    short* w_in  = (short*)(ws + 3813376);      // 3538944 bf16
    short* w_out = (short*)(ws + 5582848);      // 1769472 bf16
    short* w_pe  = (short*)(ws + 6467584);      // 147456 bf16
    float* xpwT  = ws + 6541312;                // 405504 f32
    float* dtwT  = xpwT + 405504;               // 110592 f32

    prep<<<12048, 256, 0, stream>>>(
        in_proj_w, outproj_w, pe_w, xproj_w, dtproj_w, x,
        w_in, w_out, w_pe, xpwT, dtwT, patches);
    // patch-embed + LN0 + in_proj(layer 0) fused
    gemm_ln_in<768><<<98, 256, 0, stream>>>(
        patches, w_pe, pe_b, residual, norm_w, norm_b, 0, w_in, xz);

    for (int i = 0; i < DEPTH; ++i) {
        int last = (i == DEPTH - 1);
        conv_xproj_dt<<<392, 256, 0, stream>>>(
            xz, conv_w + (size_t)i * DINNER * 4, conv_b + (size_t)i * DINNER,
            xpwT + (size_t)i * 384 * 44, dtwT + (size_t)i * 12 * 384,
            dtproj_b + (size_t)i * DINNER, ubuf, dtbuf, bcbuf);
        scan_kernel<<<192, 256, 0, stream>>>(
            ubuf, dtbuf, bcbuf, xz, A_log + (size_t)i * DINNER * DSTATE,
            D_param + (size_t)i * DINNER, ybf);
        if (!last) {
            // out_proj(i) + residual + LN(i+1) + in_proj(i+1) fused
            gemm_ln_in<384><<<98, 256, 0, stream>>>(
                ybf, w_out + (size_t)i * DMODEL * DINNER, nullptr, residual,
                norm_w + (size_t)(i + 1) * DMODEL, norm_b + (size_t)(i + 1) * DMODEL,
                1, w_in + (size_t)(i + 1) * 768 * DMODEL, xz);
        } else {
            gemm_ln<384><<<98, 256, 0, stream>>>(
                ybf, w_out + (size_t)i * DMODEL * DINNER, nullptr, residual, hn,
                (float*)d_out, normf_w, normf_b, 1);
        }
    }
}